// Round 7
// baseline (285.423 us; speedup 1.0000x reference)
//
#include <hip/hip_runtime.h>
#include <hip/hip_cooperative_groups.h>
#include <math.h>

namespace cg = cooperative_groups;

#define B 4
#define DEC 256
#define ENC 256
#define HDIM 512

// exp2(x*TANH_SCALE) == e^{2x};  tanh(x) = 1 - 2/(1+e^{2x})
#define TANH_SCALE 2.8853900817779268f
#define LOG2E 1.4426950408889634f

__device__ __forceinline__ float fast_exp2(float x) { return __builtin_amdgcn_exp2f(x); }
__device__ __forceinline__ float fast_rcp(float x)  { return __builtin_amdgcn_rcpf(x); }

typedef __attribute__((ext_vector_type(8))) short bf16x8;   // 8 bf16 = 4 VGPR
typedef __attribute__((ext_vector_type(4))) short bf16x4;
typedef __attribute__((ext_vector_type(4))) float f32x4;

__device__ __forceinline__ unsigned short bf16_rne(float x) {
    unsigned u = __float_as_uint(x);
    return (unsigned short)((u + 0x7FFFu + ((u >> 16) & 1u)) >> 16);
}
__device__ __forceinline__ float bf16_to_f(unsigned short h) {
    return __uint_as_float((unsigned)h << 16);
}

// Blocked-transpose W layout (shorts): ofs(m,k) = (m/16)*8192 + (k/8)*128 + (m%16)*8 + k%8
#define W_OFS(m, k) ((((long)(m) >> 4) << 13) + (((long)(k) >> 3) << 7) + (((m) & 15) << 3) + ((k) & 7))

// ---------------------------------------------------------------------------
// ONE cooperative kernel = convert ; grid.sync ; proj ; grid.sync ; attn_ctx.
// R6 post-mortem: ~20-25us of the 80.5us constant is inter-dispatch overhead
// (4 dispatches x ~5-8us).  Phase bodies are the verified v6 logic verbatim;
// only index derivations change:
//   convert: 512-thr block does 2 work units (g = t, t+131072; z = g>>16).
//   proj:    8 waves = 2 original 4-wave sub-blocks (P = blockIdx*2 + (w>>2)).
//   attn:    b = bidx>>6, d0 = (bidx&63)*4, rot = (bidx&63)>>3.
// grid 256 x 512 thr = 1 block/CU, all co-resident (cooperative-launch safe).
// ---------------------------------------------------------------------------
__global__ __launch_bounds__(512) void fused_kernel(
    const float* __restrict__ enc, const float* __restrict__ dec,
    const float* __restrict__ Wmlp, const float* __restrict__ bmlp,
    const float* __restrict__ wo, const unsigned char* __restrict__ extm,
    unsigned short* __restrict__ Xh_e, unsigned short* __restrict__ Xl_e,
    unsigned short* __restrict__ Xh_d, unsigned short* __restrict__ Xl_d,
    unsigned short* __restrict__ Wh_e, unsigned short* __restrict__ Wl_e,
    unsigned short* __restrict__ Wh_d, unsigned short* __restrict__ Wl_d,
    float* __restrict__ ET, float* __restrict__ Dmat,
    float* __restrict__ attn_out, float* __restrict__ ctx)
{
    __shared__ __align__(16) float ds[4][HDIM];        // 8KB   D rows
    __shared__ __align__(16) float wos[HDIM];          // 2KB   W_out
    __shared__ __align__(16) float pbuf[8][4][ENC];    // 32KB  partials (ph2/ph4)
    __shared__ __align__(16) float as4T[ENC][4];       // 4KB   probs, transposed
    __shared__ float redm[4][4];
    __shared__ float reds[4][4];

    cg::grid_group grid = cg::this_grid();
    const int tid = threadIdx.x;                       // 0..511

    // ======================= PHASE A: convert =======================
    {
        const int t = blockIdx.x * 512 + tid;          // 0..131071
#pragma unroll
        for (int u = 0; u < 2; ++u) {
            const int g = t + u * 131072;              // 0..262143
            const int z = g >> 16;                     // 0..3
            const int w = g & 0xFFFF;                  // 0..65535
            if (z < 2) {
                const float* X = z ? dec : enc;
                unsigned short* H = z ? Xh_d : Xh_e;
                unsigned short* L = z ? Xl_d : Xl_e;
                const long i8 = (long)w * 8;
                float4 v0 = *(const float4*)(X + i8);
                float4 v1 = *(const float4*)(X + i8 + 4);
                float xs[8] = {v0.x, v0.y, v0.z, v0.w, v1.x, v1.y, v1.z, v1.w};
                bf16x8 hv, lv;
#pragma unroll
                for (int j = 0; j < 8; ++j) {
                    unsigned short h = bf16_rne(xs[j]);
                    hv[j] = (short)h;
                    lv[j] = (short)bf16_rne(xs[j] - bf16_to_f(h));
                }
                *(bf16x8*)(H + i8) = hv;
                *(bf16x8*)(L + i8) = lv;
            } else {
                const float* Wsrc = Wmlp + (z == 3 ? (long)HDIM * HDIM : 0);
                unsigned short* H = (z == 3) ? Wh_d : Wh_e;
                unsigned short* L = (z == 3) ? Wl_d : Wl_e;
                const int m = w & 511;
                const int k0 = (w >> 9) << 2;
                bf16x4 hv, lv;
#pragma unroll
                for (int j = 0; j < 4; ++j) {
                    float x = Wsrc[(long)(k0 + j) * 512 + m];
                    unsigned short h = bf16_rne(x);
                    hv[j] = (short)h;
                    lv[j] = (short)bf16_rne(x - bf16_to_f(h));
                }
                const long ofs = W_OFS(m, k0);
                *(bf16x4*)(H + ofs) = hv;
                *(bf16x4*)(L + ofs) = lv;
            }
        }
    }
    __threadfence();
    grid.sync();

    // ======================= PHASE B: proj (2 sub-blocks) =======================
    {
        const int wave8 = tid >> 6, lane = tid & 63;
        const int P = blockIdx.x * 2 + (wave8 >> 2);   // 0..511 original block id
        const int wv = wave8 & 3;
        const int bx = P & 15, by = (P >> 4) & 15, z = P >> 8;
        const int r0w = bx * 64 + wv * 16;
        const int m0 = by * 32;
        const unsigned short* Xh = z ? Xh_d : Xh_e;
        const unsigned short* Xl = z ? Xl_d : Xl_e;
        const unsigned short* Wh = z ? Wh_d : Wh_e;
        const unsigned short* Wl = z ? Wl_d : Wl_e;

        const int col = lane & 15;
        const int quad = lane >> 4;

        const unsigned short* pah = Xh + (long)(r0w + col) * 512 + quad * 8;
        const unsigned short* pal = Xl + (long)(r0w + col) * 512 + quad * 8;
        const long bofs = ((long)(m0 >> 4) << 13) + (quad << 7) + (col << 3);
        const unsigned short* pb0h = Wh + bofs;
        const unsigned short* pb0l = Wl + bofs;
        const unsigned short* pb1h = Wh + bofs + 8192;
        const unsigned short* pb1l = Wl + bofs + 8192;

        f32x4 a0h = {0.f,0.f,0.f,0.f}, a0x = {0.f,0.f,0.f,0.f};
        f32x4 a1h = {0.f,0.f,0.f,0.f}, a1x = {0.f,0.f,0.f,0.f};

        bf16x8 Ah = *(const bf16x8*)pah,  Al = *(const bf16x8*)pal;
        bf16x8 B0h = *(const bf16x8*)pb0h, B0l = *(const bf16x8*)pb0l;
        bf16x8 B1h = *(const bf16x8*)pb1h, B1l = *(const bf16x8*)pb1l;

#pragma unroll 1
        for (int k0 = 0; k0 < 512; k0 += 32) {
            bf16x8 nAh = Ah, nAl = Al, nB0h = B0h, nB0l = B0l, nB1h = B1h, nB1l = B1l;
            if (k0 + 32 < 512) {
                nAh = *(const bf16x8*)(pah + k0 + 32);
                nAl = *(const bf16x8*)(pal + k0 + 32);
                const long ko = (long)(k0 + 32) << 4;
                nB0h = *(const bf16x8*)(pb0h + ko);
                nB0l = *(const bf16x8*)(pb0l + ko);
                nB1h = *(const bf16x8*)(pb1h + ko);
                nB1l = *(const bf16x8*)(pb1l + ko);
            }
            a0h = __builtin_amdgcn_mfma_f32_16x16x32_bf16(Ah, B0h, a0h, 0, 0, 0);
            a1h = __builtin_amdgcn_mfma_f32_16x16x32_bf16(Ah, B1h, a1h, 0, 0, 0);
            a0x = __builtin_amdgcn_mfma_f32_16x16x32_bf16(Ah, B0l, a0x, 0, 0, 0);
            a1x = __builtin_amdgcn_mfma_f32_16x16x32_bf16(Ah, B1l, a1x, 0, 0, 0);
            a0x = __builtin_amdgcn_mfma_f32_16x16x32_bf16(Al, B0h, a0x, 0, 0, 0);
            a1x = __builtin_amdgcn_mfma_f32_16x16x32_bf16(Al, B1h, a1x, 0, 0, 0);
            Ah = nAh; Al = nAl; B0h = nB0h; B0l = nB0l; B1h = nB1h; B1l = nB1l;
        }

        if (z == 0) {
            const int batch = r0w >> 8;
            const int e0 = (r0w & 255) + quad * 4;
            float* base = ET + (long)batch * HDIM * ENC;
            float4 v;
            v.x = fast_exp2((a0h[0] + a0x[0]) * TANH_SCALE);
            v.y = fast_exp2((a0h[1] + a0x[1]) * TANH_SCALE);
            v.z = fast_exp2((a0h[2] + a0x[2]) * TANH_SCALE);
            v.w = fast_exp2((a0h[3] + a0x[3]) * TANH_SCALE);
            *(float4*)&base[(long)(m0 + col) * ENC + e0] = v;
            v.x = fast_exp2((a1h[0] + a1x[0]) * TANH_SCALE);
            v.y = fast_exp2((a1h[1] + a1x[1]) * TANH_SCALE);
            v.z = fast_exp2((a1h[2] + a1x[2]) * TANH_SCALE);
            v.w = fast_exp2((a1h[3] + a1x[3]) * TANH_SCALE);
            *(float4*)&base[(long)(m0 + 16 + col) * ENC + e0] = v;
        } else {
            const float bq0 = bmlp[m0 + col];
            const float bq1 = bmlp[m0 + 16 + col];
            const int r = r0w + quad * 4;
#pragma unroll
            for (int i = 0; i < 4; ++i) {
                Dmat[(long)(r + i) * HDIM + m0 + col] =
                    fast_exp2((a0h[i] + a0x[i] + bq0) * TANH_SCALE);
                Dmat[(long)(r + i) * HDIM + m0 + 16 + col] =
                    fast_exp2((a1h[i] + a1x[i] + bq1) * TANH_SCALE);
            }
        }
    }
    __threadfence();
    grid.sync();

    // ======================= PHASE C: attn+softmax+ctx (v6) =======================
    {
        const int bidx = blockIdx.x;
        const int b = bidx >> 6;
        const int dblk = bidx & 63;
        const int d0 = dblk * 4;
        const long g0 = (long)b * DEC + d0;
        const int rot = dblk >> 3;

        // ---- phase 1: stage D rows + wo ----
        ((float4*)ds)[tid] = ((const float4*)(Dmat + g0 * HDIM))[tid];
        if (tid < 128) ((float4*)wos)[tid] = ((const float4*)wo)[tid];

        const int mg = ((tid >> 6) + rot) & 7;
        const int e4 = (tid & 63) * 4;
        const int mbase = mg * 64;
        const float* ep = ET + (long)b * HDIM * ENC + (long)mbase * ENC + e4;

        float4 rb[8];
#pragma unroll
        for (int j = 0; j < 8; ++j) rb[j] = *(const float4*)(ep + (long)j * ENC);
        __syncthreads();

        // ---- phase 2: 64-m reduction ----
        float acc[4][4] = {};
        for (int i = 0; i < 64; i += 4) {
            float4 c0 = rb[0], c1 = rb[1], c2 = rb[2], c3 = rb[3];
            rb[0] = rb[4]; rb[1] = rb[5]; rb[2] = rb[6]; rb[3] = rb[7];
            if (i + 8 < 64) {
#pragma unroll
                for (int j = 0; j < 4; ++j)
                    rb[4 + j] = *(const float4*)(ep + (long)(i + 8 + j) * ENC);
            }
            const int m = mbase + i;
            const float4 w4 = *(const float4*)&wos[m];
#pragma unroll
            for (int r = 0; r < 4; ++r) {
                const float4 d4 = *(const float4*)&ds[r][m];
#pragma unroll
                for (int j = 0; j < 4; ++j) {
                    acc[r][j] = fmaf(w4.x, fast_rcp(fmaf(((const float*)&c0)[j], d4.x, 1.0f)), acc[r][j]);
                    acc[r][j] = fmaf(w4.y, fast_rcp(fmaf(((const float*)&c1)[j], d4.y, 1.0f)), acc[r][j]);
                    acc[r][j] = fmaf(w4.z, fast_rcp(fmaf(((const float*)&c2)[j], d4.z, 1.0f)), acc[r][j]);
                    acc[r][j] = fmaf(w4.w, fast_rcp(fmaf(((const float*)&c3)[j], d4.w, 1.0f)), acc[r][j]);
                }
            }
        }
#pragma unroll
        for (int r = 0; r < 4; ++r) {
            float4 v = make_float4(acc[r][0], acc[r][1], acc[r][2], acc[r][3]);
            *(float4*)&pbuf[mg][r][e4] = v;
        }
        __syncthreads();

        // ---- phase 3: combine + masks + softmax ----
        const int ty = tid >> 8;
        const int e = tid & 255;
        const int wave = tid >> 6, lane = tid & 63;

        const bool pad = (enc[((long)b * ENC + e) * HDIM] == 0.0f);
        float l[2], p[2];
#pragma unroll
        for (int rl = 0; rl < 2; ++rl) {
            const int r = ty * 2 + rl;
            float a = 0.f;
#pragma unroll
            for (int q = 0; q < 8; ++q) a += pbuf[q][r][e];
            const bool xm = extm[(g0 + r) * ENC + e] != 0;
            l[rl] = (pad || xm) ? -__builtin_inff() : -2.0f * a;
        }
        float mx[2] = {l[0], l[1]};
#pragma unroll
        for (int off = 32; off >= 1; off >>= 1) {
#pragma unroll
            for (int rl = 0; rl < 2; ++rl)
                mx[rl] = fmaxf(mx[rl], __shfl_xor(mx[rl], off, 64));
        }
        if (lane == 0) {
            redm[ty * 2 + 0][wave & 3] = mx[0];
            redm[ty * 2 + 1][wave & 3] = mx[1];
        }
        __syncthreads();
        float s[2];
#pragma unroll
        for (int rl = 0; rl < 2; ++rl) {
            const int r = ty * 2 + rl;
            const float gm = fmaxf(fmaxf(redm[r][0], redm[r][1]),
                                   fmaxf(redm[r][2], redm[r][3]));
            p[rl] = fast_exp2((l[rl] - gm) * LOG2E);
            s[rl] = p[rl];
        }
#pragma unroll
        for (int off = 32; off >= 1; off >>= 1) {
#pragma unroll
            for (int rl = 0; rl < 2; ++rl)
                s[rl] += __shfl_xor(s[rl], off, 64);
        }
        if (lane == 0) {
            reds[ty * 2 + 0][wave & 3] = s[0];
            reds[ty * 2 + 1][wave & 3] = s[1];
        }
        __syncthreads();
#pragma unroll
        for (int rl = 0; rl < 2; ++rl) {
            const int r = ty * 2 + rl;
            const float gs = reds[r][0] + reds[r][1] + reds[r][2] + reds[r][3];
            const float pr = p[rl] * fast_rcp(gs);
            attn_out[(g0 + r) * ENC + e] = pr;
            as4T[e][r] = pr;
        }
        __syncthreads();

        // ---- phase 4: ctx GEMV ----
        float (*p4c)[4][HDIM] = (float (*)[4][HDIM])pbuf;

        const int hq = (tid & 127) * 4;
        const int eq = ((tid >> 7) + rot) & 3;
        const int ebase = eq * 64;
        const float* ew = enc + (long)b * ENC * HDIM + (long)ebase * HDIM + hq;

        float4 wb[8];
#pragma unroll
        for (int j = 0; j < 8; ++j) wb[j] = *(const float4*)(ew + (long)j * HDIM);

        float a4[4][4] = {};
        for (int i = 0; i < 64; i += 4) {
            float4 c0 = wb[0], c1 = wb[1], c2 = wb[2], c3 = wb[3];
            wb[0] = wb[4]; wb[1] = wb[5]; wb[2] = wb[6]; wb[3] = wb[7];
            if (i + 8 < 64) {
#pragma unroll
                for (int j = 0; j < 4; ++j)
                    wb[4 + j] = *(const float4*)(ew + (long)(i + 8 + j) * HDIM);
            }
            float4 pa = *(const float4*)&as4T[ebase + i][0];
            float4 pb = *(const float4*)&as4T[ebase + i + 1][0];
            float4 pc = *(const float4*)&as4T[ebase + i + 2][0];
            float4 pd = *(const float4*)&as4T[ebase + i + 3][0];
#pragma unroll
            for (int r = 0; r < 4; ++r) {
                const float par = ((const float*)&pa)[r];
                const float pbr = ((const float*)&pb)[r];
                const float pcr = ((const float*)&pc)[r];
                const float pdr = ((const float*)&pd)[r];
#pragma unroll
                for (int j = 0; j < 4; ++j) {
                    a4[r][j] = fmaf(par, ((const float*)&c0)[j], a4[r][j]);
                    a4[r][j] = fmaf(pbr, ((const float*)&c1)[j], a4[r][j]);
                    a4[r][j] = fmaf(pcr, ((const float*)&c2)[j], a4[r][j]);
                    a4[r][j] = fmaf(pdr, ((const float*)&c3)[j], a4[r][j]);
                }
            }
        }
#pragma unroll
        for (int r = 0; r < 4; ++r)
            *(float4*)&p4c[eq][r][hq] = make_float4(a4[r][0], a4[r][1], a4[r][2], a4[r][3]);
        __syncthreads();

        const int h = tid;
#pragma unroll
        for (int r = 0; r < 4; ++r) {
            const float o = p4c[0][r][h] + p4c[1][r][h] + p4c[2][r][h] + p4c[3][r][h];
            ctx[(g0 + r) * HDIM + h] = o;
        }
    }
}

// ---------------------------------------------------------------------------
extern "C" void kernel_launch(void* const* d_in, const int* in_sizes, int n_in,
                              void* d_out, int out_size, void* d_ws, size_t ws_size,
                              hipStream_t stream) {
    const float* dec = (const float*)d_in[0];
    const float* enc = (const float*)d_in[1];
    const unsigned char* extm = (const unsigned char*)d_in[2];
    const float* Wmlp = (const float*)d_in[3];
    const float* bmlp = (const float*)d_in[4];
    const float* Wout = (const float*)d_in[5];
    // d_in[6] = b_out: additive constant, cancels in softmax

    float* ctx = (float*)d_out;                    // [B, DEC, H]
    float* attn = ctx + (size_t)B * DEC * HDIM;    // [B, DEC, ENC]

    const size_t F = (size_t)B * DEC * HDIM;       // 524288
    float* ET = (float*)d_ws;                      // [B][H][ENC] fp32
    float* Dmat = ET + F;                          // [B*DEC][H] fp32
    unsigned short* Xh_e = (unsigned short*)(Dmat + F);
    unsigned short* Xl_e = Xh_e + F;
    unsigned short* Xh_d = Xl_e + F;
    unsigned short* Xl_d = Xh_d + F;
    unsigned short* Wh_e = Xl_d + F;               // blocked-T layout, 512*512
    unsigned short* Wl_e = Wh_e + HDIM * HDIM;
    unsigned short* Wh_d = Wl_e + HDIM * HDIM;
    unsigned short* Wl_d = Wh_d + HDIM * HDIM;

    void* kargs[] = {
        (void*)&enc, (void*)&dec, (void*)&Wmlp, (void*)&bmlp,
        (void*)&Wout, (void*)&extm,
        (void*)&Xh_e, (void*)&Xl_e, (void*)&Xh_d, (void*)&Xl_d,
        (void*)&Wh_e, (void*)&Wl_e, (void*)&Wh_d, (void*)&Wl_d,
        (void*)&ET, (void*)&Dmat, (void*)&attn, (void*)&ctx};
    hipLaunchCooperativeKernel((const void*)fused_kernel, dim3(256), dim3(512),
                               kargs, 0, stream);
}

// Round 8
// 110.487 us; speedup vs baseline: 2.5833x; 2.5833x over previous
//
#include <hip/hip_runtime.h>
#include <math.h>

#define B 4
#define DEC 256
#define ENC 256
#define HDIM 512

// exp2(x*TANH_SCALE) == e^{2x};  tanh(x) = 1 - 2/(1+e^{2x})
#define TANH_SCALE 2.8853900817779268f
#define LOG2E 1.4426950408889634f

__device__ __forceinline__ float fast_exp2(float x) { return __builtin_amdgcn_exp2f(x); }
__device__ __forceinline__ float fast_rcp(float x)  { return __builtin_amdgcn_rcpf(x); }

typedef __attribute__((ext_vector_type(8))) short bf16x8;   // 8 bf16 = 4 VGPR
typedef __attribute__((ext_vector_type(4))) short bf16x4;
typedef __attribute__((ext_vector_type(4))) float f32x4;

__device__ __forceinline__ unsigned short bf16_rne(float x) {
    unsigned u = __float_as_uint(x);
    return (unsigned short)((u + 0x7FFFu + ((u >> 16) & 1u)) >> 16);
}
__device__ __forceinline__ float bf16_to_f(unsigned short h) {
    return __uint_as_float((unsigned)h << 16);
}

// Blocked-transpose W layout (shorts): ofs(m,k) = (m/16)*8192 + (k/8)*128 + (m%16)*8 + k%8
#define W_OFS(m, k) ((((long)(m) >> 4) << 13) + (((long)(k) >> 3) << 7) + (((m) & 15) << 3) + ((k) & 7))

// ---------------------------------------------------------------------------
// convert: fp32 -> bf16 hi/lo split. (unchanged, R6)
// ---------------------------------------------------------------------------
__global__ __launch_bounds__(256) void convert_kernel(
    const float* __restrict__ enc, const float* __restrict__ dec,
    const float* __restrict__ Wmlp,
    unsigned short* __restrict__ Xh_e, unsigned short* __restrict__ Xl_e,
    unsigned short* __restrict__ Xh_d, unsigned short* __restrict__ Xl_d,
    unsigned short* __restrict__ Wh_e, unsigned short* __restrict__ Wl_e,
    unsigned short* __restrict__ Wh_d, unsigned short* __restrict__ Wl_d)
{
    const int tid = threadIdx.x, z = blockIdx.z;
    if (z < 2) {
        const float* X = z ? dec : enc;
        unsigned short* H = z ? Xh_d : Xh_e;
        unsigned short* L = z ? Xl_d : Xl_e;
        const long i8 = ((long)blockIdx.x * 256 + tid) * 8;
        float4 v0 = *(const float4*)(X + i8);
        float4 v1 = *(const float4*)(X + i8 + 4);
        float xs[8] = {v0.x, v0.y, v0.z, v0.w, v1.x, v1.y, v1.z, v1.w};
        bf16x8 hv, lv;
#pragma unroll
        for (int j = 0; j < 8; ++j) {
            unsigned short h = bf16_rne(xs[j]);
            hv[j] = (short)h;
            lv[j] = (short)bf16_rne(xs[j] - bf16_to_f(h));
        }
        *(bf16x8*)(H + i8) = hv;
        *(bf16x8*)(L + i8) = lv;
    } else {
        const float* Wsrc = Wmlp + (z == 3 ? (long)HDIM * HDIM : 0);
        unsigned short* H = (z == 3) ? Wh_d : Wh_e;
        unsigned short* L = (z == 3) ? Wl_d : Wl_e;
        const int t = blockIdx.x * 256 + tid;     // 0..65535
        const int m = t & 511;
        const int k0 = (t >> 9) << 2;             // multiple of 4
        bf16x4 hv, lv;
#pragma unroll
        for (int j = 0; j < 4; ++j) {
            float x = Wsrc[(long)(k0 + j) * 512 + m];   // coalesced reads
            unsigned short h = bf16_rne(x);
            hv[j] = (short)h;
            lv[j] = (short)bf16_rne(x - bf16_to_f(h));
        }
        const long ofs = W_OFS(m, k0);            // 4 consecutive shorts
        *(bf16x4*)(H + ofs) = hv;
        *(bf16x4*)(L + ofs) = lv;
    }
}

// ---------------------------------------------------------------------------
// proj via MFMA (unchanged, R6): wave = 16 r x 32 m, block = 64 r x 32 m.
// ---------------------------------------------------------------------------
__global__ __launch_bounds__(256) void proj_mfma_kernel(
    const unsigned short* __restrict__ Xh_e, const unsigned short* __restrict__ Xl_e,
    const unsigned short* __restrict__ Xh_d, const unsigned short* __restrict__ Xl_d,
    const unsigned short* __restrict__ Wh_e, const unsigned short* __restrict__ Wl_e,
    const unsigned short* __restrict__ Wh_d, const unsigned short* __restrict__ Wl_d,
    const float* __restrict__ bmlp,
    float* __restrict__ ET, float* __restrict__ Dmat)
{
    const int tid = threadIdx.x;
    const int wave = tid >> 6, lane = tid & 63;
    const int z = blockIdx.z;
    const int r0w = blockIdx.x * 64 + wave * 16;
    const int m0 = blockIdx.y * 32;
    const unsigned short* Xh = z ? Xh_d : Xh_e;
    const unsigned short* Xl = z ? Xl_d : Xl_e;
    const unsigned short* Wh = z ? Wh_d : Wh_e;
    const unsigned short* Wl = z ? Wl_d : Wl_e;

    const int col = lane & 15;
    const int quad = lane >> 4;

    const unsigned short* pah = Xh + (long)(r0w + col) * 512 + quad * 8;
    const unsigned short* pal = Xl + (long)(r0w + col) * 512 + quad * 8;
    const long bofs = ((long)(m0 >> 4) << 13) + (quad << 7) + (col << 3);
    const unsigned short* pb0h = Wh + bofs;
    const unsigned short* pb0l = Wl + bofs;
    const unsigned short* pb1h = Wh + bofs + 8192;
    const unsigned short* pb1l = Wl + bofs + 8192;

    f32x4 a0h = {0.f,0.f,0.f,0.f}, a0x = {0.f,0.f,0.f,0.f};
    f32x4 a1h = {0.f,0.f,0.f,0.f}, a1x = {0.f,0.f,0.f,0.f};

    bf16x8 Ah = *(const bf16x8*)pah,  Al = *(const bf16x8*)pal;
    bf16x8 B0h = *(const bf16x8*)pb0h, B0l = *(const bf16x8*)pb0l;
    bf16x8 B1h = *(const bf16x8*)pb1h, B1l = *(const bf16x8*)pb1l;

#pragma unroll 1
    for (int k0 = 0; k0 < 512; k0 += 32) {
        bf16x8 nAh = Ah, nAl = Al, nB0h = B0h, nB0l = B0l, nB1h = B1h, nB1l = B1l;
        if (k0 + 32 < 512) {
            nAh = *(const bf16x8*)(pah + k0 + 32);
            nAl = *(const bf16x8*)(pal + k0 + 32);
            const long ko = (long)(k0 + 32) << 4;
            nB0h = *(const bf16x8*)(pb0h + ko);
            nB0l = *(const bf16x8*)(pb0l + ko);
            nB1h = *(const bf16x8*)(pb1h + ko);
            nB1l = *(const bf16x8*)(pb1l + ko);
        }
        a0h = __builtin_amdgcn_mfma_f32_16x16x32_bf16(Ah, B0h, a0h, 0, 0, 0);
        a1h = __builtin_amdgcn_mfma_f32_16x16x32_bf16(Ah, B1h, a1h, 0, 0, 0);
        a0x = __builtin_amdgcn_mfma_f32_16x16x32_bf16(Ah, B0l, a0x, 0, 0, 0);
        a1x = __builtin_amdgcn_mfma_f32_16x16x32_bf16(Ah, B1l, a1x, 0, 0, 0);
        a0x = __builtin_amdgcn_mfma_f32_16x16x32_bf16(Al, B0h, a0x, 0, 0, 0);
        a1x = __builtin_amdgcn_mfma_f32_16x16x32_bf16(Al, B1h, a1x, 0, 0, 0);
        Ah = nAh; Al = nAl; B0h = nB0h; B0l = nB0l; B1h = nB1h; B1l = nB1l;
    }

    if (z == 0) {
        const int batch = r0w >> 8;
        const int e0 = (r0w & 255) + quad * 4;
        float* base = ET + (long)batch * HDIM * ENC;
        float4 v;
        v.x = fast_exp2((a0h[0] + a0x[0]) * TANH_SCALE);
        v.y = fast_exp2((a0h[1] + a0x[1]) * TANH_SCALE);
        v.z = fast_exp2((a0h[2] + a0x[2]) * TANH_SCALE);
        v.w = fast_exp2((a0h[3] + a0x[3]) * TANH_SCALE);
        *(float4*)&base[(long)(m0 + col) * ENC + e0] = v;
        v.x = fast_exp2((a1h[0] + a1x[0]) * TANH_SCALE);
        v.y = fast_exp2((a1h[1] + a1x[1]) * TANH_SCALE);
        v.z = fast_exp2((a1h[2] + a1x[2]) * TANH_SCALE);
        v.w = fast_exp2((a1h[3] + a1x[3]) * TANH_SCALE);
        *(float4*)&base[(long)(m0 + 16 + col) * ENC + e0] = v;
    } else {
        const float bq0 = bmlp[m0 + col];
        const float bq1 = bmlp[m0 + 16 + col];
        const int r = r0w + quad * 4;
#pragma unroll
        for (int i = 0; i < 4; ++i) {
            Dmat[(long)(r + i) * HDIM + m0 + col] =
                fast_exp2((a0h[i] + a0x[i] + bq0) * TANH_SCALE);
            Dmat[(long)(r + i) * HDIM + m0 + 16 + col] =
                fast_exp2((a1h[i] + a1x[i] + bq1) * TANH_SCALE);
        }
    }
}

// ---------------------------------------------------------------------------
// FUSED attn+softmax+context v7 = v6 + XCD-locality batch mapping.
// R7 lesson: cooperative grid.sync costs ~80us/sync on 8-XCD gfx950 -> dead.
// R8 theory: v6's grid (64,1,B) put all 4 batches' working sets (~10MB) on
// every XCD's 4MB L2 -> streams ran from L3 (600+cy), the latency the ring
// prefetch fought.  1-D grid of 256 with b = bidx&3: XCD = bidx%8 and
// (8k+j)&3 = j&3, so EACH XCD SERVES ONE BATCH: ET[b] 2MB + enc[b] 0.5MB +
// D rows ~= 2.75MB <= 4MB L2.  rot = dblk>>3 keeps intra-XCD de-sync.
// Phase bodies byte-identical to v6.
// ---------------------------------------------------------------------------
__global__ __launch_bounds__(512) void attn_ctx_kernel(
    const float* __restrict__ Dmat, const float* __restrict__ ET,
    const float* __restrict__ wo,
    const float* __restrict__ enc, const unsigned char* __restrict__ extm,
    float* __restrict__ attn_out, float* __restrict__ ctx)
{
    __shared__ __align__(16) float ds[4][HDIM];        // 8KB   D rows
    __shared__ __align__(16) float wos[HDIM];          // 2KB   W_out
    __shared__ __align__(16) float pbuf[8][4][ENC];    // 32KB  ph2 partials / ph4 partials
    __shared__ __align__(16) float as4T[ENC][4];       // 4KB   probs, transposed
    __shared__ float redm[4][4];
    __shared__ float reds[4][4];

    const int tid = threadIdx.x;
    const int bidx = blockIdx.x;              // 0..255
    const int b = bidx & 3;                   // XCD bidx%8 -> batch (bidx&3): 1 batch/XCD
    const int dblk = bidx >> 2;               // 0..63
    const int d0 = dblk * 4;
    const long g0 = (long)b * DEC + d0;
    const int rot = dblk >> 3;                // intra-XCD de-sync

    // ---- phase 1: stage D rows (4x512 contiguous = 8KB) + wo ----
    ((float4*)ds)[tid] = ((const float4*)(Dmat + g0 * HDIM))[tid];
    if (tid < 128) ((float4*)wos)[tid] = ((const float4*)wo)[tid];

    const int mg = ((tid >> 6) + rot) & 7;   // rotated wave -> m-group (bijective)
    const int e4 = (tid & 63) * 4;           // 4 consecutive e per thread
    const int mbase = mg * 64;
    const float* ep = ET + (long)b * HDIM * ENC + (long)mbase * ENC + e4;

    // ring prefetch: 8 rows in flight (issued before the stage barrier)
    float4 rb[8];
#pragma unroll
    for (int j = 0; j < 8; ++j) rb[j] = *(const float4*)(ep + (long)j * ENC);
    __syncthreads();

    // ---- phase 2: 64-m reduction, 4 e-cols x 4 rows/thread, 4 m per iter ----
    float acc[4][4] = {};             // [r][j]
    for (int i = 0; i < 64; i += 4) {
        float4 c0 = rb[0], c1 = rb[1], c2 = rb[2], c3 = rb[3];
        rb[0] = rb[4]; rb[1] = rb[5]; rb[2] = rb[6]; rb[3] = rb[7];
        if (i + 8 < 64) {
#pragma unroll
            for (int j = 0; j < 4; ++j)
                rb[4 + j] = *(const float4*)(ep + (long)(i + 8 + j) * ENC);
        }
        const int m = mbase + i;
        const float4 w4 = *(const float4*)&wos[m];
#pragma unroll
        for (int r = 0; r < 4; ++r) {
            const float4 d4 = *(const float4*)&ds[r][m];
#pragma unroll
            for (int j = 0; j < 4; ++j) {
                acc[r][j] = fmaf(w4.x, fast_rcp(fmaf(((const float*)&c0)[j], d4.x, 1.0f)), acc[r][j]);
                acc[r][j] = fmaf(w4.y, fast_rcp(fmaf(((const float*)&c1)[j], d4.y, 1.0f)), acc[r][j]);
                acc[r][j] = fmaf(w4.z, fast_rcp(fmaf(((const float*)&c2)[j], d4.z, 1.0f)), acc[r][j]);
                acc[r][j] = fmaf(w4.w, fast_rcp(fmaf(((const float*)&c3)[j], d4.w, 1.0f)), acc[r][j]);
            }
        }
    }
#pragma unroll
    for (int r = 0; r < 4; ++r) {
        float4 v = make_float4(acc[r][0], acc[r][1], acc[r][2], acc[r][3]);
        *(float4*)&pbuf[mg][r][e4] = v;
    }
    __syncthreads();

    // ---- phase 3: combine + masks + softmax, ALL 8 waves (2 rows each) ----
    const int ty = tid >> 8;          // 0 -> rows {0,1}, 1 -> rows {2,3}
    const int e = tid & 255;
    const int wave = tid >> 6, lane = tid & 63;

    const bool pad = (enc[((long)b * ENC + e) * HDIM] == 0.0f);
    float l[2], p[2];
#pragma unroll
    for (int rl = 0; rl < 2; ++rl) {
        const int r = ty * 2 + rl;
        float a = 0.f;
#pragma unroll
        for (int q = 0; q < 8; ++q) a += pbuf[q][r][e];
        const bool xm = extm[(g0 + r) * ENC + e] != 0;
        l[rl] = (pad || xm) ? -__builtin_inff() : -2.0f * a;
    }
    float mx[2] = {l[0], l[1]};
#pragma unroll
    for (int off = 32; off >= 1; off >>= 1) {
#pragma unroll
        for (int rl = 0; rl < 2; ++rl)
            mx[rl] = fmaxf(mx[rl], __shfl_xor(mx[rl], off, 64));
    }
    if (lane == 0) {
        redm[ty * 2 + 0][wave & 3] = mx[0];
        redm[ty * 2 + 1][wave & 3] = mx[1];
    }
    __syncthreads();
    float s[2];
#pragma unroll
    for (int rl = 0; rl < 2; ++rl) {
        const int r = ty * 2 + rl;
        const float gm = fmaxf(fmaxf(redm[r][0], redm[r][1]),
                               fmaxf(redm[r][2], redm[r][3]));
        p[rl] = fast_exp2((l[rl] - gm) * LOG2E);
        s[rl] = p[rl];
    }
#pragma unroll
    for (int off = 32; off >= 1; off >>= 1) {
#pragma unroll
        for (int rl = 0; rl < 2; ++rl)
            s[rl] += __shfl_xor(s[rl], off, 64);
    }
    if (lane == 0) {
        reds[ty * 2 + 0][wave & 3] = s[0];
        reds[ty * 2 + 1][wave & 3] = s[1];
    }
    __syncthreads();
#pragma unroll
    for (int rl = 0; rl < 2; ++rl) {
        const int r = ty * 2 + rl;
        const float gs = reds[r][0] + reds[r][1] + reds[r][2] + reds[r][3];
        const float pr = p[rl] * fast_rcp(gs);
        attn_out[(g0 + r) * ENC + e] = pr;
        as4T[e][r] = pr;
    }
    __syncthreads();

    // ---- phase 4: ctx GEMV, thread = (4 h-cols, e-quarter); depth-8 ring ----
    float (*p4c)[4][HDIM] = (float (*)[4][HDIM])pbuf;   // [eq][r][h], 32KB alias

    const int hq = (tid & 127) * 4;                  // 0..508
    const int eq = ((tid >> 7) + rot) & 3;           // rotated e-quarter
    const int ebase = eq * 64;
    const float* ew = enc + (long)b * ENC * HDIM + (long)ebase * HDIM + hq;

    float4 wb[8];
#pragma unroll
    for (int j = 0; j < 8; ++j) wb[j] = *(const float4*)(ew + (long)j * HDIM);

    float a4[4][4] = {};              // [r][j]
    for (int i = 0; i < 64; i += 4) {
        float4 c0 = wb[0], c1 = wb[1], c2 = wb[2], c3 = wb[3];
        wb[0] = wb[4]; wb[1] = wb[5]; wb[2] = wb[6]; wb[3] = wb[7];
        if (i + 8 < 64) {
#pragma unroll
            for (int j = 0; j < 4; ++j)
                wb[4 + j] = *(const float4*)(ew + (long)(i + 8 + j) * HDIM);
        }
        float4 pa = *(const float4*)&as4T[ebase + i][0];       // broadcast b128
        float4 pb = *(const float4*)&as4T[ebase + i + 1][0];
        float4 pc = *(const float4*)&as4T[ebase + i + 2][0];
        float4 pd = *(const float4*)&as4T[ebase + i + 3][0];
#pragma unroll
        for (int r = 0; r < 4; ++r) {
            const float par = ((const float*)&pa)[r];
            const float pbr = ((const float*)&pb)[r];
            const float pcr = ((const float*)&pc)[r];
            const float pdr = ((const float*)&pd)[r];
#pragma unroll
            for (int j = 0; j < 4; ++j) {
                a4[r][j] = fmaf(par, ((const float*)&c0)[j], a4[r][j]);
                a4[r][j] = fmaf(pbr, ((const float*)&c1)[j], a4[r][j]);
                a4[r][j] = fmaf(pcr, ((const float*)&c2)[j], a4[r][j]);
                a4[r][j] = fmaf(pdr, ((const float*)&c3)[j], a4[r][j]);
            }
        }
    }
#pragma unroll
    for (int r = 0; r < 4; ++r)
        *(float4*)&p4c[eq][r][hq] = make_float4(a4[r][0], a4[r][1], a4[r][2], a4[r][3]);
    __syncthreads();

    // final combine: thread = h
    const int h = tid;
#pragma unroll
    for (int r = 0; r < 4; ++r) {
        const float o = p4c[0][r][h] + p4c[1][r][h] + p4c[2][r][h] + p4c[3][r][h];
        ctx[(g0 + r) * HDIM + h] = o;
    }
}

// ---------------------------------------------------------------------------
extern "C" void kernel_launch(void* const* d_in, const int* in_sizes, int n_in,
                              void* d_out, int out_size, void* d_ws, size_t ws_size,
                              hipStream_t stream) {
    const float* dec = (const float*)d_in[0];
    const float* enc = (const float*)d_in[1];
    const unsigned char* extm = (const unsigned char*)d_in[2];
    const float* Wmlp = (const float*)d_in[3];
    const float* bmlp = (const float*)d_in[4];
    const float* Wout = (const float*)d_in[5];
    // d_in[6] = b_out: additive constant, cancels in softmax

    float* ctx = (float*)d_out;                    // [B, DEC, H]
    float* attn = ctx + (size_t)B * DEC * HDIM;    // [B, DEC, ENC]

    const size_t F = (size_t)B * DEC * HDIM;       // 524288
    float* ET = (float*)d_ws;                      // [B][H][ENC] fp32
    float* Dmat = ET + F;                          // [B*DEC][H] fp32
    unsigned short* Xh_e = (unsigned short*)(Dmat + F);
    unsigned short* Xl_e = Xh_e + F;
    unsigned short* Xh_d = Xl_e + F;
    unsigned short* Xl_d = Xh_d + F;
    unsigned short* Wh_e = Xl_d + F;               // blocked-T layout, 512*512
    unsigned short* Wl_e = Wh_e + HDIM * HDIM;
    unsigned short* Wh_d = Wl_e + HDIM * HDIM;
    unsigned short* Wl_d = Wh_d + HDIM * HDIM;

    convert_kernel<<<dim3(256, 1, 4), 256, 0, stream>>>(
        enc, dec, Wmlp, Xh_e, Xl_e, Xh_d, Xl_d, Wh_e, Wl_e, Wh_d, Wl_d);
    proj_mfma_kernel<<<dim3(16, 16, 2), 256, 0, stream>>>(
        Xh_e, Xl_e, Xh_d, Xl_d, Wh_e, Wl_e, Wh_d, Wl_d, bmlp, ET, Dmat);
    attn_ctx_kernel<<<dim3(256, 1, 1), 512, 0, stream>>>(
        Dmat, ET, Wout, enc, extm, attn, ctx);
}

// Round 9
// 104.857 us; speedup vs baseline: 2.7220x; 1.0537x over previous
//
#include <hip/hip_runtime.h>
#include <math.h>

#define B 4
#define DEC 256
#define ENC 256
#define HDIM 512

// exp2(x*TANH_SCALE) == e^{2x};  tanh(x) = 1 - 2/(1+e^{2x})
#define TANH_SCALE 2.8853900817779268f
#define LOG2E 1.4426950408889634f

__device__ __forceinline__ float fast_exp2(float x) { return __builtin_amdgcn_exp2f(x); }
__device__ __forceinline__ float fast_rcp(float x)  { return __builtin_amdgcn_rcpf(x); }

typedef __attribute__((ext_vector_type(8))) short bf16x8;   // 8 bf16 = 4 VGPR
typedef __attribute__((ext_vector_type(4))) short bf16x4;
typedef __attribute__((ext_vector_type(4))) float f32x4;

__device__ __forceinline__ unsigned short bf16_rne(float x) {
    unsigned u = __float_as_uint(x);
    return (unsigned short)((u + 0x7FFFu + ((u >> 16) & 1u)) >> 16);
}
__device__ __forceinline__ float bf16_to_f(unsigned short h) {
    return __uint_as_float((unsigned)h << 16);
}

// Blocked-transpose W layout (shorts): ofs(m,k) = (m/16)*8192 + (k/8)*128 + (m%16)*8 + k%8
#define W_OFS(m, k) ((((long)(m) >> 4) << 13) + (((long)(k) >> 3) << 7) + (((m) & 15) << 3) + ((k) & 7))

// ---------------------------------------------------------------------------
// convert: fp32 -> bf16 hi/lo split. (unchanged, R6)
// ---------------------------------------------------------------------------
__global__ __launch_bounds__(256) void convert_kernel(
    const float* __restrict__ enc, const float* __restrict__ dec,
    const float* __restrict__ Wmlp,
    unsigned short* __restrict__ Xh_e, unsigned short* __restrict__ Xl_e,
    unsigned short* __restrict__ Xh_d, unsigned short* __restrict__ Xl_d,
    unsigned short* __restrict__ Wh_e, unsigned short* __restrict__ Wl_e,
    unsigned short* __restrict__ Wh_d, unsigned short* __restrict__ Wl_d)
{
    const int tid = threadIdx.x, z = blockIdx.z;
    if (z < 2) {
        const float* X = z ? dec : enc;
        unsigned short* H = z ? Xh_d : Xh_e;
        unsigned short* L = z ? Xl_d : Xl_e;
        const long i8 = ((long)blockIdx.x * 256 + tid) * 8;
        float4 v0 = *(const float4*)(X + i8);
        float4 v1 = *(const float4*)(X + i8 + 4);
        float xs[8] = {v0.x, v0.y, v0.z, v0.w, v1.x, v1.y, v1.z, v1.w};
        bf16x8 hv, lv;
#pragma unroll
        for (int j = 0; j < 8; ++j) {
            unsigned short h = bf16_rne(xs[j]);
            hv[j] = (short)h;
            lv[j] = (short)bf16_rne(xs[j] - bf16_to_f(h));
        }
        *(bf16x8*)(H + i8) = hv;
        *(bf16x8*)(L + i8) = lv;
    } else {
        const float* Wsrc = Wmlp + (z == 3 ? (long)HDIM * HDIM : 0);
        unsigned short* H = (z == 3) ? Wh_d : Wh_e;
        unsigned short* L = (z == 3) ? Wl_d : Wl_e;
        const int t = blockIdx.x * 256 + tid;     // 0..65535
        const int m = t & 511;
        const int k0 = (t >> 9) << 2;             // multiple of 4
        bf16x4 hv, lv;
#pragma unroll
        for (int j = 0; j < 4; ++j) {
            float x = Wsrc[(long)(k0 + j) * 512 + m];   // coalesced reads
            unsigned short h = bf16_rne(x);
            hv[j] = (short)h;
            lv[j] = (short)bf16_rne(x - bf16_to_f(h));
        }
        const long ofs = W_OFS(m, k0);            // 4 consecutive shorts
        *(bf16x4*)(H + ofs) = hv;
        *(bf16x4*)(L + ofs) = lv;
    }
}

// ---------------------------------------------------------------------------
// proj via MFMA (unchanged, R6): wave = 16 r x 32 m, block = 64 r x 32 m.
// ---------------------------------------------------------------------------
__global__ __launch_bounds__(256) void proj_mfma_kernel(
    const unsigned short* __restrict__ Xh_e, const unsigned short* __restrict__ Xl_e,
    const unsigned short* __restrict__ Xh_d, const unsigned short* __restrict__ Xl_d,
    const unsigned short* __restrict__ Wh_e, const unsigned short* __restrict__ Wl_e,
    const unsigned short* __restrict__ Wh_d, const unsigned short* __restrict__ Wl_d,
    const float* __restrict__ bmlp,
    float* __restrict__ ET, float* __restrict__ Dmat)
{
    const int tid = threadIdx.x;
    const int wave = tid >> 6, lane = tid & 63;
    const int z = blockIdx.z;
    const int r0w = blockIdx.x * 64 + wave * 16;
    const int m0 = blockIdx.y * 32;
    const unsigned short* Xh = z ? Xh_d : Xh_e;
    const unsigned short* Xl = z ? Xl_d : Xl_e;
    const unsigned short* Wh = z ? Wh_d : Wh_e;
    const unsigned short* Wl = z ? Wl_d : Wl_e;

    const int col = lane & 15;
    const int quad = lane >> 4;

    const unsigned short* pah = Xh + (long)(r0w + col) * 512 + quad * 8;
    const unsigned short* pal = Xl + (long)(r0w + col) * 512 + quad * 8;
    const long bofs = ((long)(m0 >> 4) << 13) + (quad << 7) + (col << 3);
    const unsigned short* pb0h = Wh + bofs;
    const unsigned short* pb0l = Wl + bofs;
    const unsigned short* pb1h = Wh + bofs + 8192;
    const unsigned short* pb1l = Wl + bofs + 8192;

    f32x4 a0h = {0.f,0.f,0.f,0.f}, a0x = {0.f,0.f,0.f,0.f};
    f32x4 a1h = {0.f,0.f,0.f,0.f}, a1x = {0.f,0.f,0.f,0.f};

    bf16x8 Ah = *(const bf16x8*)pah,  Al = *(const bf16x8*)pal;
    bf16x8 B0h = *(const bf16x8*)pb0h, B0l = *(const bf16x8*)pb0l;
    bf16x8 B1h = *(const bf16x8*)pb1h, B1l = *(const bf16x8*)pb1l;

#pragma unroll 1
    for (int k0 = 0; k0 < 512; k0 += 32) {
        bf16x8 nAh = Ah, nAl = Al, nB0h = B0h, nB0l = B0l, nB1h = B1h, nB1l = B1l;
        if (k0 + 32 < 512) {
            nAh = *(const bf16x8*)(pah + k0 + 32);
            nAl = *(const bf16x8*)(pal + k0 + 32);
            const long ko = (long)(k0 + 32) << 4;
            nB0h = *(const bf16x8*)(pb0h + ko);
            nB0l = *(const bf16x8*)(pb0l + ko);
            nB1h = *(const bf16x8*)(pb1h + ko);
            nB1l = *(const bf16x8*)(pb1l + ko);
        }
        a0h = __builtin_amdgcn_mfma_f32_16x16x32_bf16(Ah, B0h, a0h, 0, 0, 0);
        a1h = __builtin_amdgcn_mfma_f32_16x16x32_bf16(Ah, B1h, a1h, 0, 0, 0);
        a0x = __builtin_amdgcn_mfma_f32_16x16x32_bf16(Ah, B0l, a0x, 0, 0, 0);
        a1x = __builtin_amdgcn_mfma_f32_16x16x32_bf16(Ah, B1l, a1x, 0, 0, 0);
        a0x = __builtin_amdgcn_mfma_f32_16x16x32_bf16(Al, B0h, a0x, 0, 0, 0);
        a1x = __builtin_amdgcn_mfma_f32_16x16x32_bf16(Al, B1h, a1x, 0, 0, 0);
        Ah = nAh; Al = nAl; B0h = nB0h; B0l = nB0l; B1h = nB1h; B1l = nB1l;
    }

    if (z == 0) {
        const int batch = r0w >> 8;
        const int e0 = (r0w & 255) + quad * 4;
        float* base = ET + (long)batch * HDIM * ENC;
        float4 v;
        v.x = fast_exp2((a0h[0] + a0x[0]) * TANH_SCALE);
        v.y = fast_exp2((a0h[1] + a0x[1]) * TANH_SCALE);
        v.z = fast_exp2((a0h[2] + a0x[2]) * TANH_SCALE);
        v.w = fast_exp2((a0h[3] + a0x[3]) * TANH_SCALE);
        *(float4*)&base[(long)(m0 + col) * ENC + e0] = v;
        v.x = fast_exp2((a1h[0] + a1x[0]) * TANH_SCALE);
        v.y = fast_exp2((a1h[1] + a1x[1]) * TANH_SCALE);
        v.z = fast_exp2((a1h[2] + a1x[2]) * TANH_SCALE);
        v.w = fast_exp2((a1h[3] + a1x[3]) * TANH_SCALE);
        *(float4*)&base[(long)(m0 + 16 + col) * ENC + e0] = v;
    } else {
        const float bq0 = bmlp[m0 + col];
        const float bq1 = bmlp[m0 + 16 + col];
        const int r = r0w + quad * 4;
#pragma unroll
        for (int i = 0; i < 4; ++i) {
            Dmat[(long)(r + i) * HDIM + m0 + col] =
                fast_exp2((a0h[i] + a0x[i] + bq0) * TANH_SCALE);
            Dmat[(long)(r + i) * HDIM + m0 + 16 + col] =
                fast_exp2((a1h[i] + a1x[i] + bq1) * TANH_SCALE);
        }
    }
}

// ---------------------------------------------------------------------------
// FUSED attn+softmax+context v8 = R6's v6 + QUAD-RCP reduction in phase 2.
// R8 null result (XCD-batch map ~0) killed all memory-side theories; the
// stall profile (VALUBusy 40%, MfmaUtil 0, HBM 6%, every prefetch lever
// flat) fits a TRANS-EXECUTION bound: 134M v_rcp_f32 at >=16cy/wave-instr.
// Fix is algebraic: batch 4 m-terms per reciprocal,
//   sum_i w_i/t_i = (n01*p23 + n23*p01) / (p01*p23),
//   t_i = 1+E_i*D_i, p01=t0t1, p23=t2t3, n01=w0t1+w1t0, n23=w2t3+w3t2.
// Per 4 m: 1 rcp + 14 VALU (was 4 rcp + 8 VALU) -> trans work / 4.
// Numerics: a_i = e^{2x}, x~N(0,0.64) -> quad products <= ~1e13, safe fp32.
// Grid/rot/rings byte-identical to R6 (measured best, 108.4).
// ---------------------------------------------------------------------------
__global__ __launch_bounds__(512) void attn_ctx_kernel(
    const float* __restrict__ Dmat, const float* __restrict__ ET,
    const float* __restrict__ wo,
    const float* __restrict__ enc, const unsigned char* __restrict__ extm,
    float* __restrict__ attn_out, float* __restrict__ ctx)
{
    __shared__ __align__(16) float ds[4][HDIM];        // 8KB   D rows
    __shared__ __align__(16) float wos[HDIM];          // 2KB   W_out
    __shared__ __align__(16) float pbuf[8][4][ENC];    // 32KB  ph2 partials / ph4 partials
    __shared__ __align__(16) float as4T[ENC][4];       // 4KB   probs, transposed
    __shared__ float redm[4][4];
    __shared__ float reds[4][4];

    const int tid = threadIdx.x;
    const int b = blockIdx.z, d0 = blockIdx.x * 4;
    const long g0 = (long)b * DEC + d0;
    const int rot = blockIdx.x >> 3;   // same-XCD de-sync (blocks x, x+8,... differ)

    // ---- phase 1: stage D rows (4x512 contiguous = 8KB) + wo ----
    ((float4*)ds)[tid] = ((const float4*)(Dmat + g0 * HDIM))[tid];
    if (tid < 128) ((float4*)wos)[tid] = ((const float4*)wo)[tid];

    const int mg = ((tid >> 6) + rot) & 7;   // rotated wave -> m-group (bijective)
    const int e4 = (tid & 63) * 4;           // 4 consecutive e per thread
    const int mbase = mg * 64;
    const float* ep = ET + (long)b * HDIM * ENC + (long)mbase * ENC + e4;

    // ring prefetch: 8 rows in flight (issued before the stage barrier)
    float4 rb[8];
#pragma unroll
    for (int j = 0; j < 8; ++j) rb[j] = *(const float4*)(ep + (long)j * ENC);
    __syncthreads();

    // ---- phase 2: 64-m reduction, quad-rcp: 1 rcp per 4 m ----
    float acc[4][4] = {};             // [r][j]
    for (int i = 0; i < 64; i += 4) {
        float4 c0 = rb[0], c1 = rb[1], c2 = rb[2], c3 = rb[3];
        rb[0] = rb[4]; rb[1] = rb[5]; rb[2] = rb[6]; rb[3] = rb[7];
        if (i + 8 < 64) {
#pragma unroll
            for (int j = 0; j < 4; ++j)
                rb[4 + j] = *(const float4*)(ep + (long)(i + 8 + j) * ENC);
        }
        const int m = mbase + i;
        const float4 w4 = *(const float4*)&wos[m];
#pragma unroll
        for (int r = 0; r < 4; ++r) {
            const float4 d4 = *(const float4*)&ds[r][m];
#pragma unroll
            for (int j = 0; j < 4; ++j) {
                const float t0 = fmaf(((const float*)&c0)[j], d4.x, 1.0f);
                const float t1 = fmaf(((const float*)&c1)[j], d4.y, 1.0f);
                const float t2 = fmaf(((const float*)&c2)[j], d4.z, 1.0f);
                const float t3 = fmaf(((const float*)&c3)[j], d4.w, 1.0f);
                const float p01 = t0 * t1;
                const float p23 = t2 * t3;
                const float n01 = fmaf(w4.x, t1, w4.y * t0);
                const float n23 = fmaf(w4.z, t3, w4.w * t2);
                const float N = fmaf(n01, p23, n23 * p01);
                acc[r][j] = fmaf(N, fast_rcp(p01 * p23), acc[r][j]);
            }
        }
    }
#pragma unroll
    for (int r = 0; r < 4; ++r) {
        float4 v = make_float4(acc[r][0], acc[r][1], acc[r][2], acc[r][3]);
        *(float4*)&pbuf[mg][r][e4] = v;
    }
    __syncthreads();

    // ---- phase 3: combine + masks + softmax, ALL 8 waves (2 rows each) ----
    const int ty = tid >> 8;          // 0 -> rows {0,1}, 1 -> rows {2,3}
    const int e = tid & 255;
    const int wave = tid >> 6, lane = tid & 63;

    const bool pad = (enc[((long)b * ENC + e) * HDIM] == 0.0f);
    float l[2], p[2];
#pragma unroll
    for (int rl = 0; rl < 2; ++rl) {
        const int r = ty * 2 + rl;
        float a = 0.f;
#pragma unroll
        for (int q = 0; q < 8; ++q) a += pbuf[q][r][e];
        const bool xm = extm[(g0 + r) * ENC + e] != 0;
        l[rl] = (pad || xm) ? -__builtin_inff() : -2.0f * a;
    }
    float mx[2] = {l[0], l[1]};
#pragma unroll
    for (int off = 32; off >= 1; off >>= 1) {
#pragma unroll
        for (int rl = 0; rl < 2; ++rl)
            mx[rl] = fmaxf(mx[rl], __shfl_xor(mx[rl], off, 64));
    }
    if (lane == 0) {
        redm[ty * 2 + 0][wave & 3] = mx[0];
        redm[ty * 2 + 1][wave & 3] = mx[1];
    }
    __syncthreads();
    float s[2];
#pragma unroll
    for (int rl = 0; rl < 2; ++rl) {
        const int r = ty * 2 + rl;
        const float gm = fmaxf(fmaxf(redm[r][0], redm[r][1]),
                               fmaxf(redm[r][2], redm[r][3]));
        p[rl] = fast_exp2((l[rl] - gm) * LOG2E);
        s[rl] = p[rl];
    }
#pragma unroll
    for (int off = 32; off >= 1; off >>= 1) {
#pragma unroll
        for (int rl = 0; rl < 2; ++rl)
            s[rl] += __shfl_xor(s[rl], off, 64);
    }
    if (lane == 0) {
        reds[ty * 2 + 0][wave & 3] = s[0];
        reds[ty * 2 + 1][wave & 3] = s[1];
    }
    __syncthreads();
#pragma unroll
    for (int rl = 0; rl < 2; ++rl) {
        const int r = ty * 2 + rl;
        const float gs = reds[r][0] + reds[r][1] + reds[r][2] + reds[r][3];
        const float pr = p[rl] * fast_rcp(gs);
        attn_out[(g0 + r) * ENC + e] = pr;
        as4T[e][r] = pr;
    }
    __syncthreads();

    // ---- phase 4: ctx GEMV, thread = (4 h-cols, e-quarter); depth-8 ring ----
    float (*p4c)[4][HDIM] = (float (*)[4][HDIM])pbuf;   // [eq][r][h], 32KB alias

    const int hq = (tid & 127) * 4;                  // 0..508
    const int eq = ((tid >> 7) + rot) & 3;           // rotated e-quarter
    const int ebase = eq * 64;
    const float* ew = enc + (long)b * ENC * HDIM + (long)ebase * HDIM + hq;

    float4 wb[8];
#pragma unroll
    for (int j = 0; j < 8; ++j) wb[j] = *(const float4*)(ew + (long)j * HDIM);

    float a4[4][4] = {};              // [r][j]
    for (int i = 0; i < 64; i += 4) {
        float4 c0 = wb[0], c1 = wb[1], c2 = wb[2], c3 = wb[3];
        wb[0] = wb[4]; wb[1] = wb[5]; wb[2] = wb[6]; wb[3] = wb[7];
        if (i + 8 < 64) {
#pragma unroll
            for (int j = 0; j < 4; ++j)
                wb[4 + j] = *(const float4*)(ew + (long)(i + 8 + j) * HDIM);
        }
        float4 pa = *(const float4*)&as4T[ebase + i][0];       // broadcast b128
        float4 pb = *(const float4*)&as4T[ebase + i + 1][0];
        float4 pc = *(const float4*)&as4T[ebase + i + 2][0];
        float4 pd = *(const float4*)&as4T[ebase + i + 3][0];
#pragma unroll
        for (int r = 0; r < 4; ++r) {
            const float par = ((const float*)&pa)[r];
            const float pbr = ((const float*)&pb)[r];
            const float pcr = ((const float*)&pc)[r];
            const float pdr = ((const float*)&pd)[r];
#pragma unroll
            for (int j = 0; j < 4; ++j) {
                a4[r][j] = fmaf(par, ((const float*)&c0)[j], a4[r][j]);
                a4[r][j] = fmaf(pbr, ((const float*)&c1)[j], a4[r][j]);
                a4[r][j] = fmaf(pcr, ((const float*)&c2)[j], a4[r][j]);
                a4[r][j] = fmaf(pdr, ((const float*)&c3)[j], a4[r][j]);
            }
        }
    }
#pragma unroll
    for (int r = 0; r < 4; ++r)
        *(float4*)&p4c[eq][r][hq] = make_float4(a4[r][0], a4[r][1], a4[r][2], a4[r][3]);
    __syncthreads();

    // final combine: thread = h
    const int h = tid;
#pragma unroll
    for (int r = 0; r < 4; ++r) {
        const float o = p4c[0][r][h] + p4c[1][r][h] + p4c[2][r][h] + p4c[3][r][h];
        ctx[(g0 + r) * HDIM + h] = o;
    }
}

// ---------------------------------------------------------------------------
extern "C" void kernel_launch(void* const* d_in, const int* in_sizes, int n_in,
                              void* d_out, int out_size, void* d_ws, size_t ws_size,
                              hipStream_t stream) {
    const float* dec = (const float*)d_in[0];
    const float* enc = (const float*)d_in[1];
    const unsigned char* extm = (const unsigned char*)d_in[2];
    const float* Wmlp = (const float*)d_in[3];
    const float* bmlp = (const float*)d_in[4];
    const float* Wout = (const float*)d_in[5];
    // d_in[6] = b_out: additive constant, cancels in softmax

    float* ctx = (float*)d_out;                    // [B, DEC, H]
    float* attn = ctx + (size_t)B * DEC * HDIM;    // [B, DEC, ENC]

    const size_t F = (size_t)B * DEC * HDIM;       // 524288
    float* ET = (float*)d_ws;                      // [B][H][ENC] fp32
    float* Dmat = ET + F;                          // [B*DEC][H] fp32
    unsigned short* Xh_e = (unsigned short*)(Dmat + F);
    unsigned short* Xl_e = Xh_e + F;
    unsigned short* Xh_d = Xl_e + F;
    unsigned short* Xl_d = Xh_d + F;
    unsigned short* Wh_e = Xl_d + F;               // blocked-T layout, 512*512
    unsigned short* Wl_e = Wh_e + HDIM * HDIM;
    unsigned short* Wh_d = Wl_e + HDIM * HDIM;
    unsigned short* Wl_d = Wh_d + HDIM * HDIM;

    convert_kernel<<<dim3(256, 1, 4), 256, 0, stream>>>(
        enc, dec, Wmlp, Xh_e, Xl_e, Xh_d, Xl_d, Wh_e, Wl_e, Wh_d, Wl_d);
    proj_mfma_kernel<<<dim3(16, 16, 2), 256, 0, stream>>>(
        Xh_e, Xl_e, Xh_d, Xl_d, Wh_e, Wl_e, Wh_d, Wl_d, bmlp, ET, Dmat);
    attn_ctx_kernel<<<dim3(DEC / 4, 1, B), 512, 0, stream>>>(
        Dmat, ET, Wout, enc, extm, attn, ctx);
}

// Round 10
// 104.018 us; speedup vs baseline: 2.7440x; 1.0081x over previous
//
#include <hip/hip_runtime.h>
#include <math.h>

#define B 4
#define DEC 256
#define ENC 256
#define HDIM 512

// exp2(x*TANH_SCALE) == e^{2x};  tanh(x) = 1 - 2/(1+e^{2x})
#define TANH_SCALE 2.8853900817779268f
#define LOG2E 1.4426950408889634f

__device__ __forceinline__ float fast_exp2(float x) { return __builtin_amdgcn_exp2f(x); }
__device__ __forceinline__ float fast_rcp(float x)  { return __builtin_amdgcn_rcpf(x); }

typedef __attribute__((ext_vector_type(8))) short bf16x8;   // 8 bf16 = 4 VGPR
typedef __attribute__((ext_vector_type(4))) short bf16x4;
typedef __attribute__((ext_vector_type(4))) float f32x4;

__device__ __forceinline__ unsigned short bf16_rne(float x) {
    unsigned u = __float_as_uint(x);
    return (unsigned short)((u + 0x7FFFu + ((u >> 16) & 1u)) >> 16);
}
__device__ __forceinline__ float bf16_to_f(unsigned short h) {
    return __uint_as_float((unsigned)h << 16);
}

// Blocked-transpose W layout (shorts): ofs(m,k) = (m/16)*8192 + (k/8)*128 + (m%16)*8 + k%8
#define W_OFS(m, k) ((((long)(m) >> 4) << 13) + (((long)(k) >> 3) << 7) + (((m) & 15) << 3) + ((k) & 7))

// ---------------------------------------------------------------------------
// convert: fp32 -> bf16 hi/lo split. (unchanged)
// ---------------------------------------------------------------------------
__global__ __launch_bounds__(256) void convert_kernel(
    const float* __restrict__ enc, const float* __restrict__ dec,
    const float* __restrict__ Wmlp,
    unsigned short* __restrict__ Xh_e, unsigned short* __restrict__ Xl_e,
    unsigned short* __restrict__ Xh_d, unsigned short* __restrict__ Xl_d,
    unsigned short* __restrict__ Wh_e, unsigned short* __restrict__ Wl_e,
    unsigned short* __restrict__ Wh_d, unsigned short* __restrict__ Wl_d)
{
    const int tid = threadIdx.x, z = blockIdx.z;
    if (z < 2) {
        const float* X = z ? dec : enc;
        unsigned short* H = z ? Xh_d : Xh_e;
        unsigned short* L = z ? Xl_d : Xl_e;
        const long i8 = ((long)blockIdx.x * 256 + tid) * 8;
        float4 v0 = *(const float4*)(X + i8);
        float4 v1 = *(const float4*)(X + i8 + 4);
        float xs[8] = {v0.x, v0.y, v0.z, v0.w, v1.x, v1.y, v1.z, v1.w};
        bf16x8 hv, lv;
#pragma unroll
        for (int j = 0; j < 8; ++j) {
            unsigned short h = bf16_rne(xs[j]);
            hv[j] = (short)h;
            lv[j] = (short)bf16_rne(xs[j] - bf16_to_f(h));
        }
        *(bf16x8*)(H + i8) = hv;
        *(bf16x8*)(L + i8) = lv;
    } else {
        const float* Wsrc = Wmlp + (z == 3 ? (long)HDIM * HDIM : 0);
        unsigned short* H = (z == 3) ? Wh_d : Wh_e;
        unsigned short* L = (z == 3) ? Wl_d : Wl_e;
        const int t = blockIdx.x * 256 + tid;     // 0..65535
        const int m = t & 511;
        const int k0 = (t >> 9) << 2;             // multiple of 4
        bf16x4 hv, lv;
#pragma unroll
        for (int j = 0; j < 4; ++j) {
            float x = Wsrc[(long)(k0 + j) * 512 + m];   // coalesced reads
            unsigned short h = bf16_rne(x);
            hv[j] = (short)h;
            lv[j] = (short)bf16_rne(x - bf16_to_f(h));
        }
        const long ofs = W_OFS(m, k0);            // 4 consecutive shorts
        *(bf16x4*)(H + ofs) = hv;
        *(bf16x4*)(L + ofs) = lv;
    }
}

// ---------------------------------------------------------------------------
// proj via MFMA (unchanged): wave = 16 r x 32 m, block = 64 r x 32 m.
// ---------------------------------------------------------------------------
__global__ __launch_bounds__(256) void proj_mfma_kernel(
    const unsigned short* __restrict__ Xh_e, const unsigned short* __restrict__ Xl_e,
    const unsigned short* __restrict__ Xh_d, const unsigned short* __restrict__ Xl_d,
    const unsigned short* __restrict__ Wh_e, const unsigned short* __restrict__ Wl_e,
    const unsigned short* __restrict__ Wh_d, const unsigned short* __restrict__ Wl_d,
    const float* __restrict__ bmlp,
    float* __restrict__ ET, float* __restrict__ Dmat)
{
    const int tid = threadIdx.x;
    const int wave = tid >> 6, lane = tid & 63;
    const int z = blockIdx.z;
    const int r0w = blockIdx.x * 64 + wave * 16;
    const int m0 = blockIdx.y * 32;
    const unsigned short* Xh = z ? Xh_d : Xh_e;
    const unsigned short* Xl = z ? Xl_d : Xl_e;
    const unsigned short* Wh = z ? Wh_d : Wh_e;
    const unsigned short* Wl = z ? Wl_d : Wl_e;

    const int col = lane & 15;
    const int quad = lane >> 4;

    const unsigned short* pah = Xh + (long)(r0w + col) * 512 + quad * 8;
    const unsigned short* pal = Xl + (long)(r0w + col) * 512 + quad * 8;
    const long bofs = ((long)(m0 >> 4) << 13) + (quad << 7) + (col << 3);
    const unsigned short* pb0h = Wh + bofs;
    const unsigned short* pb0l = Wl + bofs;
    const unsigned short* pb1h = Wh + bofs + 8192;
    const unsigned short* pb1l = Wl + bofs + 8192;

    f32x4 a0h = {0.f,0.f,0.f,0.f}, a0x = {0.f,0.f,0.f,0.f};
    f32x4 a1h = {0.f,0.f,0.f,0.f}, a1x = {0.f,0.f,0.f,0.f};

    bf16x8 Ah = *(const bf16x8*)pah,  Al = *(const bf16x8*)pal;
    bf16x8 B0h = *(const bf16x8*)pb0h, B0l = *(const bf16x8*)pb0l;
    bf16x8 B1h = *(const bf16x8*)pb1h, B1l = *(const bf16x8*)pb1l;

#pragma unroll 1
    for (int k0 = 0; k0 < 512; k0 += 32) {
        bf16x8 nAh = Ah, nAl = Al, nB0h = B0h, nB0l = B0l, nB1h = B1h, nB1l = B1l;
        if (k0 + 32 < 512) {
            nAh = *(const bf16x8*)(pah + k0 + 32);
            nAl = *(const bf16x8*)(pal + k0 + 32);
            const long ko = (long)(k0 + 32) << 4;
            nB0h = *(const bf16x8*)(pb0h + ko);
            nB0l = *(const bf16x8*)(pb0l + ko);
            nB1h = *(const bf16x8*)(pb1h + ko);
            nB1l = *(const bf16x8*)(pb1l + ko);
        }
        a0h = __builtin_amdgcn_mfma_f32_16x16x32_bf16(Ah, B0h, a0h, 0, 0, 0);
        a1h = __builtin_amdgcn_mfma_f32_16x16x32_bf16(Ah, B1h, a1h, 0, 0, 0);
        a0x = __builtin_amdgcn_mfma_f32_16x16x32_bf16(Ah, B0l, a0x, 0, 0, 0);
        a1x = __builtin_amdgcn_mfma_f32_16x16x32_bf16(Ah, B1l, a1x, 0, 0, 0);
        a0x = __builtin_amdgcn_mfma_f32_16x16x32_bf16(Al, B0h, a0x, 0, 0, 0);
        a1x = __builtin_amdgcn_mfma_f32_16x16x32_bf16(Al, B1h, a1x, 0, 0, 0);
        Ah = nAh; Al = nAl; B0h = nB0h; B0l = nB0l; B1h = nB1h; B1l = nB1l;
    }

    if (z == 0) {
        const int batch = r0w >> 8;
        const int e0 = (r0w & 255) + quad * 4;
        float* base = ET + (long)batch * HDIM * ENC;
        float4 v;
        v.x = fast_exp2((a0h[0] + a0x[0]) * TANH_SCALE);
        v.y = fast_exp2((a0h[1] + a0x[1]) * TANH_SCALE);
        v.z = fast_exp2((a0h[2] + a0x[2]) * TANH_SCALE);
        v.w = fast_exp2((a0h[3] + a0x[3]) * TANH_SCALE);
        *(float4*)&base[(long)(m0 + col) * ENC + e0] = v;
        v.x = fast_exp2((a1h[0] + a1x[0]) * TANH_SCALE);
        v.y = fast_exp2((a1h[1] + a1x[1]) * TANH_SCALE);
        v.z = fast_exp2((a1h[2] + a1x[2]) * TANH_SCALE);
        v.w = fast_exp2((a1h[3] + a1x[3]) * TANH_SCALE);
        *(float4*)&base[(long)(m0 + 16 + col) * ENC + e0] = v;
    } else {
        const float bq0 = bmlp[m0 + col];
        const float bq1 = bmlp[m0 + 16 + col];
        const int r = r0w + quad * 4;
#pragma unroll
        for (int i = 0; i < 4; ++i) {
            Dmat[(long)(r + i) * HDIM + m0 + col] =
                fast_exp2((a0h[i] + a0x[i] + bq0) * TANH_SCALE);
            Dmat[(long)(r + i) * HDIM + m0 + 16 + col] =
                fast_exp2((a1h[i] + a1x[i] + bq1) * TANH_SCALE);
        }
    }
}

// ---------------------------------------------------------------------------
// FUSED attn+softmax+context v9 = v8 (quad-rcp) + NAMED PING-PONG buffers.
// R9 residual: attn ~24.4us vs ~10-11us issue model.  Last untested
// mechanism: the register-rotation ring (rb[0]=rb[4]...) can force v_movs +
// conservative vmcnt drains per iteration (m97-style).  v9: two NAMED
// 4-row buffer sets per stream loop, no rotation copies -> per-buffer
// dependency chains, per-buffer waitcnt.  8 m (or 8 e) per iteration.
// Phase-4's first 8 enc rows are issued BEFORE phase 3 (LDS-independent)
// so softmax hides their latency.  Quad-rcp and grid unchanged from R9.
// ---------------------------------------------------------------------------
__global__ __launch_bounds__(512) void attn_ctx_kernel(
    const float* __restrict__ Dmat, const float* __restrict__ ET,
    const float* __restrict__ wo,
    const float* __restrict__ enc, const unsigned char* __restrict__ extm,
    float* __restrict__ attn_out, float* __restrict__ ctx)
{
    __shared__ __align__(16) float ds[4][HDIM];        // 8KB   D rows
    __shared__ __align__(16) float wos[HDIM];          // 2KB   W_out
    __shared__ __align__(16) float pbuf[8][4][ENC];    // 32KB  ph2 partials / ph4 partials
    __shared__ __align__(16) float as4T[ENC][4];       // 4KB   probs, transposed
    __shared__ float redm[4][4];
    __shared__ float reds[4][4];

    const int tid = threadIdx.x;
    const int b = blockIdx.z, d0 = blockIdx.x * 4;
    const long g0 = (long)b * DEC + d0;
    const int rot = blockIdx.x >> 3;   // same-XCD de-sync (blocks x, x+8,... differ)

    // ---- phase 1: stage D rows (4x512 contiguous = 8KB) + wo ----
    ((float4*)ds)[tid] = ((const float4*)(Dmat + g0 * HDIM))[tid];
    if (tid < 128) ((float4*)wos)[tid] = ((const float4*)wo)[tid];

    const int mg = ((tid >> 6) + rot) & 7;   // rotated wave -> m-group (bijective)
    const int e4 = (tid & 63) * 4;           // 4 consecutive e per thread
    const int mbase = mg * 64;
    const float* ep = ET + (long)b * HDIM * ENC + (long)mbase * ENC + e4;

#define LDE(k) (*(const float4*)(ep + (long)(k) * ENC))
    // named ping-pong sets (no rotation copies)
    float4 EA0 = LDE(0), EA1 = LDE(1), EA2 = LDE(2), EA3 = LDE(3);
    float4 EB0 = LDE(4), EB1 = LDE(5), EB2 = LDE(6), EB3 = LDE(7);
    __syncthreads();

    // ---- phase 2: 64-m reduction, quad-rcp, 8 m per iteration ----
    float acc[4][4] = {};             // [r][j]

#define PH2_QUAD(C0, C1, C2, C3, M)                                          \
    {                                                                        \
        const float4 w4 = *(const float4*)&wos[(M)];                         \
        _Pragma("unroll")                                                    \
        for (int r = 0; r < 4; ++r) {                                        \
            const float4 d4 = *(const float4*)&ds[r][(M)];                   \
            _Pragma("unroll")                                                \
            for (int j = 0; j < 4; ++j) {                                    \
                const float t0 = fmaf(((const float*)&C0)[j], d4.x, 1.0f);   \
                const float t1 = fmaf(((const float*)&C1)[j], d4.y, 1.0f);   \
                const float t2 = fmaf(((const float*)&C2)[j], d4.z, 1.0f);   \
                const float t3 = fmaf(((const float*)&C3)[j], d4.w, 1.0f);   \
                const float p01 = t0 * t1;                                   \
                const float p23 = t2 * t3;                                   \
                const float n01 = fmaf(w4.x, t1, w4.y * t0);                 \
                const float n23 = fmaf(w4.z, t3, w4.w * t2);                 \
                const float N = fmaf(n01, p23, n23 * p01);                   \
                acc[r][j] = fmaf(N, fast_rcp(p01 * p23), acc[r][j]);         \
            }                                                                \
        }                                                                    \
    }

#pragma unroll 1
    for (int i = 0; i < 64; i += 8) {
        PH2_QUAD(EA0, EA1, EA2, EA3, mbase + i)
        if (i + 8 < 64) {
            EA0 = LDE(i + 8);  EA1 = LDE(i + 9);
            EA2 = LDE(i + 10); EA3 = LDE(i + 11);
        }
        PH2_QUAD(EB0, EB1, EB2, EB3, mbase + i + 4)
        if (i + 8 < 64) {
            EB0 = LDE(i + 12); EB1 = LDE(i + 13);
            EB2 = LDE(i + 14); EB3 = LDE(i + 15);
        }
    }
#pragma unroll
    for (int r = 0; r < 4; ++r) {
        float4 v = make_float4(acc[r][0], acc[r][1], acc[r][2], acc[r][3]);
        *(float4*)&pbuf[mg][r][e4] = v;
    }

    // ---- early-issue phase-4's first 8 enc rows (LDS-independent) ----
    const int hq = (tid & 127) * 4;                  // 0..508
    const int eq = ((tid >> 7) + rot) & 3;           // rotated e-quarter
    const int ebase = eq * 64;
    const float* ew = enc + (long)b * ENC * HDIM + (long)ebase * HDIM + hq;
#define LDW(k) (*(const float4*)(ew + (long)(k) * HDIM))
    float4 WA0 = LDW(0), WA1 = LDW(1), WA2 = LDW(2), WA3 = LDW(3);
    float4 WB0 = LDW(4), WB1 = LDW(5), WB2 = LDW(6), WB3 = LDW(7);

    __syncthreads();

    // ---- phase 3: combine + masks + softmax, ALL 8 waves (2 rows each) ----
    const int ty = tid >> 8;          // 0 -> rows {0,1}, 1 -> rows {2,3}
    const int e = tid & 255;
    const int wave = tid >> 6, lane = tid & 63;

    const bool pad = (enc[((long)b * ENC + e) * HDIM] == 0.0f);
    float l[2], p[2];
#pragma unroll
    for (int rl = 0; rl < 2; ++rl) {
        const int r = ty * 2 + rl;
        float a = 0.f;
#pragma unroll
        for (int q = 0; q < 8; ++q) a += pbuf[q][r][e];
        const bool xm = extm[(g0 + r) * ENC + e] != 0;
        l[rl] = (pad || xm) ? -__builtin_inff() : -2.0f * a;
    }
    float mx[2] = {l[0], l[1]};
#pragma unroll
    for (int off = 32; off >= 1; off >>= 1) {
#pragma unroll
        for (int rl = 0; rl < 2; ++rl)
            mx[rl] = fmaxf(mx[rl], __shfl_xor(mx[rl], off, 64));
    }
    if (lane == 0) {
        redm[ty * 2 + 0][wave & 3] = mx[0];
        redm[ty * 2 + 1][wave & 3] = mx[1];
    }
    __syncthreads();
    float s[2];
#pragma unroll
    for (int rl = 0; rl < 2; ++rl) {
        const int r = ty * 2 + rl;
        const float gm = fmaxf(fmaxf(redm[r][0], redm[r][1]),
                               fmaxf(redm[r][2], redm[r][3]));
        p[rl] = fast_exp2((l[rl] - gm) * LOG2E);
        s[rl] = p[rl];
    }
#pragma unroll
    for (int off = 32; off >= 1; off >>= 1) {
#pragma unroll
        for (int rl = 0; rl < 2; ++rl)
            s[rl] += __shfl_xor(s[rl], off, 64);
    }
    if (lane == 0) {
        reds[ty * 2 + 0][wave & 3] = s[0];
        reds[ty * 2 + 1][wave & 3] = s[1];
    }
    __syncthreads();
#pragma unroll
    for (int rl = 0; rl < 2; ++rl) {
        const int r = ty * 2 + rl;
        const float gs = reds[r][0] + reds[r][1] + reds[r][2] + reds[r][3];
        const float pr = p[rl] * fast_rcp(gs);
        attn_out[(g0 + r) * ENC + e] = pr;
        as4T[e][r] = pr;
    }
    __syncthreads();

    // ---- phase 4: ctx GEMV, ping-pong named sets, 8 e per iteration ----
    float (*p4c)[4][HDIM] = (float (*)[4][HDIM])pbuf;   // [eq][r][h], 32KB alias

    float a4[4][4] = {};              // [r][j]

#define PH4_QUAD(C0, C1, C2, C3, E0)                                         \
    {                                                                        \
        const float4 pa = *(const float4*)&as4T[(E0) + 0][0];                \
        const float4 pb = *(const float4*)&as4T[(E0) + 1][0];                \
        const float4 pc = *(const float4*)&as4T[(E0) + 2][0];                \
        const float4 pd = *(const float4*)&as4T[(E0) + 3][0];                \
        _Pragma("unroll")                                                    \
        for (int r = 0; r < 4; ++r) {                                        \
            const float par = ((const float*)&pa)[r];                        \
            const float pbr = ((const float*)&pb)[r];                        \
            const float pcr = ((const float*)&pc)[r];                        \
            const float pdr = ((const float*)&pd)[r];                        \
            _Pragma("unroll")                                                \
            for (int j = 0; j < 4; ++j) {                                    \
                a4[r][j] = fmaf(par, ((const float*)&C0)[j], a4[r][j]);      \
                a4[r][j] = fmaf(pbr, ((const float*)&C1)[j], a4[r][j]);      \
                a4[r][j] = fmaf(pcr, ((const float*)&C2)[j], a4[r][j]);      \
                a4[r][j] = fmaf(pdr, ((const float*)&C3)[j], a4[r][j]);      \
            }                                                                \
        }                                                                    \
    }

#pragma unroll 1
    for (int i = 0; i < 64; i += 8) {
        PH4_QUAD(WA0, WA1, WA2, WA3, ebase + i)
        if (i + 8 < 64) {
            WA0 = LDW(i + 8);  WA1 = LDW(i + 9);
            WA2 = LDW(i + 10); WA3 = LDW(i + 11);
        }
        PH4_QUAD(WB0, WB1, WB2, WB3, ebase + i + 4)
        if (i + 8 < 64) {
            WB0 = LDW(i + 12); WB1 = LDW(i + 13);
            WB2 = LDW(i + 14); WB3 = LDW(i + 15);
        }
    }
#pragma unroll
    for (int r = 0; r < 4; ++r)
        *(float4*)&p4c[eq][r][hq] = make_float4(a4[r][0], a4[r][1], a4[r][2], a4[r][3]);
    __syncthreads();

    // final combine: thread = h
    const int h = tid;
#pragma unroll
    for (int r = 0; r < 4; ++r) {
        const float o = p4c[0][r][h] + p4c[1][r][h] + p4c[2][r][h] + p4c[3][r][h];
        ctx[(g0 + r) * HDIM + h] = o;
    }
}

// ---------------------------------------------------------------------------
extern "C" void kernel_launch(void* const* d_in, const int* in_sizes, int n_in,
                              void* d_out, int out_size, void* d_ws, size_t ws_size,
                              hipStream_t stream) {
    const float* dec = (const float*)d_in[0];
    const float* enc = (const float*)d_in[1];
    const unsigned char* extm = (const unsigned char*)d_in[2];
    const float* Wmlp = (const float*)d_in[3];
    const float* bmlp = (const float*)d_in[4];
    const float* Wout = (const float*)d_in[5];
    // d_in[6] = b_out: additive constant, cancels in softmax

    float* ctx = (float*)d_out;                    // [B, DEC, H]
    float* attn = ctx + (size_t)B * DEC * HDIM;    // [B, DEC, ENC]

    const size_t F = (size_t)B * DEC * HDIM;       // 524288
    float* ET = (float*)d_ws;                      // [B][H][ENC] fp32
    float* Dmat = ET + F;                          // [B*DEC][H] fp32
    unsigned short* Xh_e = (unsigned short*)(Dmat + F);
    unsigned short* Xl_e = Xh_e + F;
    unsigned short* Xh_d = Xl_e + F;
    unsigned short* Xl_d = Xh_d + F;
    unsigned short* Wh_e = Xl_d + F;               // blocked-T layout, 512*512
    unsigned short* Wl_e = Wh_e + HDIM * HDIM;
    unsigned short* Wh_d = Wl_e + HDIM * HDIM;
    unsigned short* Wl_d = Wh_d + HDIM * HDIM;

    convert_kernel<<<dim3(256, 1, 4), 256, 0, stream>>>(
        enc, dec, Wmlp, Xh_e, Xl_e, Xh_d, Xl_d, Wh_e, Wl_e, Wh_d, Wl_d);
    proj_mfma_kernel<<<dim3(16, 16, 2), 256, 0, stream>>>(
        Xh_e, Xl_e, Xh_d, Xl_d, Wh_e, Wl_e, Wh_d, Wl_d, bmlp, ET, Dmat);
    attn_ctx_kernel<<<dim3(DEC / 4, 1, B), 512, 0, stream>>>(
        Dmat, ET, Wout, enc, extm, attn, ctx);
}

// Round 11
// 103.861 us; speedup vs baseline: 2.7481x; 1.0015x over previous
//
#include <hip/hip_runtime.h>
#include <math.h>

#define B 4
#define DEC 256
#define ENC 256
#define HDIM 512

// exp2(x*TANH_SCALE) == e^{2x};  tanh(x) = 1 - 2/(1+e^{2x})
#define TANH_SCALE 2.8853900817779268f
#define LOG2E 1.4426950408889634f

__device__ __forceinline__ float fast_exp2(float x) { return __builtin_amdgcn_exp2f(x); }
__device__ __forceinline__ float fast_rcp(float x)  { return __builtin_amdgcn_rcpf(x); }

typedef __attribute__((ext_vector_type(8))) short bf16x8;   // 8 bf16 = 4 VGPR
typedef __attribute__((ext_vector_type(4))) short bf16x4;
typedef __attribute__((ext_vector_type(4))) float f32x4;

__device__ __forceinline__ unsigned short bf16_rne(float x) {
    unsigned u = __float_as_uint(x);
    return (unsigned short)((u + 0x7FFFu + ((u >> 16) & 1u)) >> 16);
}
__device__ __forceinline__ float bf16_to_f(unsigned short h) {
    return __uint_as_float((unsigned)h << 16);
}

// Blocked-transpose W layout (shorts): ofs(m,k) = (m/16)*8192 + (k/8)*128 + (m%16)*8 + k%8
#define W_OFS(m, k) ((((long)(m) >> 4) << 13) + (((long)(k) >> 3) << 7) + (((m) & 15) << 3) + ((k) & 7))

// ---------------------------------------------------------------------------
// convert: fp32 -> bf16 hi/lo split. (unchanged)
// ---------------------------------------------------------------------------
__global__ __launch_bounds__(256) void convert_kernel(
    const float* __restrict__ enc, const float* __restrict__ dec,
    const float* __restrict__ Wmlp,
    unsigned short* __restrict__ Xh_e, unsigned short* __restrict__ Xl_e,
    unsigned short* __restrict__ Xh_d, unsigned short* __restrict__ Xl_d,
    unsigned short* __restrict__ Wh_e, unsigned short* __restrict__ Wl_e,
    unsigned short* __restrict__ Wh_d, unsigned short* __restrict__ Wl_d)
{
    const int tid = threadIdx.x, z = blockIdx.z;
    if (z < 2) {
        const float* X = z ? dec : enc;
        unsigned short* H = z ? Xh_d : Xh_e;
        unsigned short* L = z ? Xl_d : Xl_e;
        const long i8 = ((long)blockIdx.x * 256 + tid) * 8;
        float4 v0 = *(const float4*)(X + i8);
        float4 v1 = *(const float4*)(X + i8 + 4);
        float xs[8] = {v0.x, v0.y, v0.z, v0.w, v1.x, v1.y, v1.z, v1.w};
        bf16x8 hv, lv;
#pragma unroll
        for (int j = 0; j < 8; ++j) {
            unsigned short h = bf16_rne(xs[j]);
            hv[j] = (short)h;
            lv[j] = (short)bf16_rne(xs[j] - bf16_to_f(h));
        }
        *(bf16x8*)(H + i8) = hv;
        *(bf16x8*)(L + i8) = lv;
    } else {
        const float* Wsrc = Wmlp + (z == 3 ? (long)HDIM * HDIM : 0);
        unsigned short* H = (z == 3) ? Wh_d : Wh_e;
        unsigned short* L = (z == 3) ? Wl_d : Wl_e;
        const int t = blockIdx.x * 256 + tid;     // 0..65535
        const int m = t & 511;
        const int k0 = (t >> 9) << 2;             // multiple of 4
        bf16x4 hv, lv;
#pragma unroll
        for (int j = 0; j < 4; ++j) {
            float x = Wsrc[(long)(k0 + j) * 512 + m];   // coalesced reads
            unsigned short h = bf16_rne(x);
            hv[j] = (short)h;
            lv[j] = (short)bf16_rne(x - bf16_to_f(h));
        }
        const long ofs = W_OFS(m, k0);            // 4 consecutive shorts
        *(bf16x4*)(H + ofs) = hv;
        *(bf16x4*)(L + ofs) = lv;
    }
}

// ---------------------------------------------------------------------------
// proj via MFMA (unchanged): wave = 16 r x 32 m, block = 64 r x 32 m.
// ---------------------------------------------------------------------------
__global__ __launch_bounds__(256) void proj_mfma_kernel(
    const unsigned short* __restrict__ Xh_e, const unsigned short* __restrict__ Xl_e,
    const unsigned short* __restrict__ Xh_d, const unsigned short* __restrict__ Xl_d,
    const unsigned short* __restrict__ Wh_e, const unsigned short* __restrict__ Wl_e,
    const unsigned short* __restrict__ Wh_d, const unsigned short* __restrict__ Wl_d,
    const float* __restrict__ bmlp,
    float* __restrict__ ET, float* __restrict__ Dmat)
{
    const int tid = threadIdx.x;
    const int wave = tid >> 6, lane = tid & 63;
    const int z = blockIdx.z;
    const int r0w = blockIdx.x * 64 + wave * 16;
    const int m0 = blockIdx.y * 32;
    const unsigned short* Xh = z ? Xh_d : Xh_e;
    const unsigned short* Xl = z ? Xl_d : Xl_e;
    const unsigned short* Wh = z ? Wh_d : Wh_e;
    const unsigned short* Wl = z ? Wl_d : Wl_e;

    const int col = lane & 15;
    const int quad = lane >> 4;

    const unsigned short* pah = Xh + (long)(r0w + col) * 512 + quad * 8;
    const unsigned short* pal = Xl + (long)(r0w + col) * 512 + quad * 8;
    const long bofs = ((long)(m0 >> 4) << 13) + (quad << 7) + (col << 3);
    const unsigned short* pb0h = Wh + bofs;
    const unsigned short* pb0l = Wl + bofs;
    const unsigned short* pb1h = Wh + bofs + 8192;
    const unsigned short* pb1l = Wl + bofs + 8192;

    f32x4 a0h = {0.f,0.f,0.f,0.f}, a0x = {0.f,0.f,0.f,0.f};
    f32x4 a1h = {0.f,0.f,0.f,0.f}, a1x = {0.f,0.f,0.f,0.f};

    bf16x8 Ah = *(const bf16x8*)pah,  Al = *(const bf16x8*)pal;
    bf16x8 B0h = *(const bf16x8*)pb0h, B0l = *(const bf16x8*)pb0l;
    bf16x8 B1h = *(const bf16x8*)pb1h, B1l = *(const bf16x8*)pb1l;

#pragma unroll 1
    for (int k0 = 0; k0 < 512; k0 += 32) {
        bf16x8 nAh = Ah, nAl = Al, nB0h = B0h, nB0l = B0l, nB1h = B1h, nB1l = B1l;
        if (k0 + 32 < 512) {
            nAh = *(const bf16x8*)(pah + k0 + 32);
            nAl = *(const bf16x8*)(pal + k0 + 32);
            const long ko = (long)(k0 + 32) << 4;
            nB0h = *(const bf16x8*)(pb0h + ko);
            nB0l = *(const bf16x8*)(pb0l + ko);
            nB1h = *(const bf16x8*)(pb1h + ko);
            nB1l = *(const bf16x8*)(pb1l + ko);
        }
        a0h = __builtin_amdgcn_mfma_f32_16x16x32_bf16(Ah, B0h, a0h, 0, 0, 0);
        a1h = __builtin_amdgcn_mfma_f32_16x16x32_bf16(Ah, B1h, a1h, 0, 0, 0);
        a0x = __builtin_amdgcn_mfma_f32_16x16x32_bf16(Ah, B0l, a0x, 0, 0, 0);
        a1x = __builtin_amdgcn_mfma_f32_16x16x32_bf16(Ah, B1l, a1x, 0, 0, 0);
        a0x = __builtin_amdgcn_mfma_f32_16x16x32_bf16(Al, B0h, a0x, 0, 0, 0);
        a1x = __builtin_amdgcn_mfma_f32_16x16x32_bf16(Al, B1h, a1x, 0, 0, 0);
        Ah = nAh; Al = nAl; B0h = nB0h; B0l = nB0l; B1h = nB1h; B1l = nB1l;
    }

    if (z == 0) {
        const int batch = r0w >> 8;
        const int e0 = (r0w & 255) + quad * 4;
        float* base = ET + (long)batch * HDIM * ENC;
        float4 v;
        v.x = fast_exp2((a0h[0] + a0x[0]) * TANH_SCALE);
        v.y = fast_exp2((a0h[1] + a0x[1]) * TANH_SCALE);
        v.z = fast_exp2((a0h[2] + a0x[2]) * TANH_SCALE);
        v.w = fast_exp2((a0h[3] + a0x[3]) * TANH_SCALE);
        *(float4*)&base[(long)(m0 + col) * ENC + e0] = v;
        v.x = fast_exp2((a1h[0] + a1x[0]) * TANH_SCALE);
        v.y = fast_exp2((a1h[1] + a1x[1]) * TANH_SCALE);
        v.z = fast_exp2((a1h[2] + a1x[2]) * TANH_SCALE);
        v.w = fast_exp2((a1h[3] + a1x[3]) * TANH_SCALE);
        *(float4*)&base[(long)(m0 + 16 + col) * ENC + e0] = v;
    } else {
        const float bq0 = bmlp[m0 + col];
        const float bq1 = bmlp[m0 + 16 + col];
        const int r = r0w + quad * 4;
#pragma unroll
        for (int i = 0; i < 4; ++i) {
            Dmat[(long)(r + i) * HDIM + m0 + col] =
                fast_exp2((a0h[i] + a0x[i] + bq0) * TANH_SCALE);
            Dmat[(long)(r + i) * HDIM + m0 + 16 + col] =
                fast_exp2((a1h[i] + a1x[i] + bq1) * TANH_SCALE);
        }
    }
}

// ---------------------------------------------------------------------------
// FUSED attn+softmax+context v10 = v9 (quad-rcp + ping-pong) at 1024 THREADS.
// R10 null (ping-pong ~0) + post-quad-rcp mix (11 VALU : 1 trans) means the
// kernel is VALU-issue/dep-latency bound at only 2 waves/SIMD (VALUBusy 40%).
// R4's occupancy attempt failed because more BLOCKS duplicated per-block
// ET/enc streams; more WAVES per block duplicates nothing.  v10: 16 waves =
// 4 waves/SIMD (2x TLP), same 256 blocks, same traffic, same math.
//   phase 2: 16 m-groups of 32 m; pbuf[16][4][256] = 64KB (LDS total 78KB).
//   phase 3: 4 row-quarters, 1 row each (same shfl+redm pattern).
//   phase 4: 8 e-eighths of 32 e; p4c[8][4][512] aliases pbuf; final
//            combine: thread = (h, row-pair).
// ---------------------------------------------------------------------------
__global__ __launch_bounds__(1024) void attn_ctx_kernel(
    const float* __restrict__ Dmat, const float* __restrict__ ET,
    const float* __restrict__ wo,
    const float* __restrict__ enc, const unsigned char* __restrict__ extm,
    float* __restrict__ attn_out, float* __restrict__ ctx)
{
    __shared__ __align__(16) float ds[4][HDIM];        // 8KB   D rows
    __shared__ __align__(16) float wos[HDIM];          // 2KB   W_out
    __shared__ __align__(16) float pbuf[16][4][ENC];   // 64KB  ph2 partials / ph4 alias
    __shared__ __align__(16) float as4T[ENC][4];       // 4KB   probs, transposed
    __shared__ float redm[4][4];
    __shared__ float reds[4][4];

    const int tid = threadIdx.x;               // 0..1023
    const int b = blockIdx.z, d0 = blockIdx.x * 4;
    const long g0 = (long)b * DEC + d0;
    const int rot = blockIdx.x >> 3;   // same-XCD de-sync

    // ---- phase 1: stage D rows (4x512 contiguous = 8KB) + wo ----
    if (tid < 512) ((float4*)ds)[tid] = ((const float4*)(Dmat + g0 * HDIM))[tid];
    if (tid < 128) ((float4*)wos)[tid] = ((const float4*)wo)[tid];

    const int mg = ((tid >> 6) + rot) & 15;  // rotated wave -> m-group (bijective)
    const int e4 = (tid & 63) * 4;           // 4 consecutive e per thread
    const int mbase = mg * 32;
    const float* ep = ET + (long)b * HDIM * ENC + (long)mbase * ENC + e4;

#define LDE(k) (*(const float4*)(ep + (long)(k) * ENC))
    // named ping-pong sets (no rotation copies)
    float4 EA0 = LDE(0), EA1 = LDE(1), EA2 = LDE(2), EA3 = LDE(3);
    float4 EB0 = LDE(4), EB1 = LDE(5), EB2 = LDE(6), EB3 = LDE(7);
    __syncthreads();

    // ---- phase 2: 32-m reduction, quad-rcp, 8 m per iteration ----
    float acc[4][4] = {};             // [r][j]

#define PH2_QUAD(C0, C1, C2, C3, M)                                          \
    {                                                                        \
        const float4 w4 = *(const float4*)&wos[(M)];                         \
        _Pragma("unroll")                                                    \
        for (int r = 0; r < 4; ++r) {                                        \
            const float4 d4 = *(const float4*)&ds[r][(M)];                   \
            _Pragma("unroll")                                                \
            for (int j = 0; j < 4; ++j) {                                    \
                const float t0 = fmaf(((const float*)&C0)[j], d4.x, 1.0f);   \
                const float t1 = fmaf(((const float*)&C1)[j], d4.y, 1.0f);   \
                const float t2 = fmaf(((const float*)&C2)[j], d4.z, 1.0f);   \
                const float t3 = fmaf(((const float*)&C3)[j], d4.w, 1.0f);   \
                const float p01 = t0 * t1;                                   \
                const float p23 = t2 * t3;                                   \
                const float n01 = fmaf(w4.x, t1, w4.y * t0);                 \
                const float n23 = fmaf(w4.z, t3, w4.w * t2);                 \
                const float N = fmaf(n01, p23, n23 * p01);                   \
                acc[r][j] = fmaf(N, fast_rcp(p01 * p23), acc[r][j]);         \
            }                                                                \
        }                                                                    \
    }

#pragma unroll 1
    for (int i = 0; i < 32; i += 8) {
        PH2_QUAD(EA0, EA1, EA2, EA3, mbase + i)
        if (i + 8 < 32) {
            EA0 = LDE(i + 8);  EA1 = LDE(i + 9);
            EA2 = LDE(i + 10); EA3 = LDE(i + 11);
        }
        PH2_QUAD(EB0, EB1, EB2, EB3, mbase + i + 4)
        if (i + 8 < 32) {
            EB0 = LDE(i + 12); EB1 = LDE(i + 13);
            EB2 = LDE(i + 14); EB3 = LDE(i + 15);
        }
    }
#pragma unroll
    for (int r = 0; r < 4; ++r) {
        float4 v = make_float4(acc[r][0], acc[r][1], acc[r][2], acc[r][3]);
        *(float4*)&pbuf[mg][r][e4] = v;
    }

    // ---- early-issue phase-4's first 8 enc rows (LDS-independent) ----
    const int hq = (tid & 127) * 4;                  // 0..508
    const int eq = ((tid >> 7) + rot) & 7;           // rotated e-eighth
    const int ebase = eq * 32;
    const float* ew = enc + (long)b * ENC * HDIM + (long)ebase * HDIM + hq;
#define LDW(k) (*(const float4*)(ew + (long)(k) * HDIM))
    float4 WA0 = LDW(0), WA1 = LDW(1), WA2 = LDW(2), WA3 = LDW(3);
    float4 WB0 = LDW(4), WB1 = LDW(5), WB2 = LDW(6), WB3 = LDW(7);

    __syncthreads();

    // ---- phase 3: combine + masks + softmax, 4 row-quarters (1 row each) ----
    const int rq = tid >> 8;          // 0..3 -> row rq
    const int e = tid & 255;
    const int wave = tid >> 6, lane = tid & 63;

    const bool pad = (enc[((long)b * ENC + e) * HDIM] == 0.0f);
    float l, p;
    {
        float a = 0.f;
#pragma unroll
        for (int q = 0; q < 16; ++q) a += pbuf[q][rq][e];
        const bool xm = extm[(g0 + rq) * ENC + e] != 0;
        l = (pad || xm) ? -__builtin_inff() : -2.0f * a;
    }
    float mx = l;
#pragma unroll
    for (int off = 32; off >= 1; off >>= 1)
        mx = fmaxf(mx, __shfl_xor(mx, off, 64));
    if (lane == 0) redm[rq][wave & 3] = mx;
    __syncthreads();
    {
        const float gm = fmaxf(fmaxf(redm[rq][0], redm[rq][1]),
                               fmaxf(redm[rq][2], redm[rq][3]));
        p = fast_exp2((l - gm) * LOG2E);
    }
    float s = p;
#pragma unroll
    for (int off = 32; off >= 1; off >>= 1)
        s += __shfl_xor(s, off, 64);
    if (lane == 0) reds[rq][wave & 3] = s;
    __syncthreads();
    {
        const float gs = reds[rq][0] + reds[rq][1] + reds[rq][2] + reds[rq][3];
        const float pr = p * fast_rcp(gs);
        attn_out[(g0 + rq) * ENC + e] = pr;
        as4T[e][rq] = pr;
    }
    __syncthreads();

    // ---- phase 4: ctx GEMV, ping-pong named sets, 8 e per iteration ----
    float (*p4c)[4][HDIM] = (float (*)[4][HDIM])pbuf;   // [eq][r][h], 64KB alias

    float a4[4][4] = {};              // [r][j]

#define PH4_QUAD(C0, C1, C2, C3, E0)                                         \
    {                                                                        \
        const float4 pa = *(const float4*)&as4T[(E0) + 0][0];                \
        const float4 pb = *(const float4*)&as4T[(E0) + 1][0];                \
        const float4 pc = *(const float4*)&as4T[(E0) + 2][0];                \
        const float4 pd = *(const float4*)&as4T[(E0) + 3][0];                \
        _Pragma("unroll")                                                    \
        for (int r = 0; r < 4; ++r) {                                        \
            const float par = ((const float*)&pa)[r];                        \
            const float pbr = ((const float*)&pb)[r];                        \
            const float pcr = ((const float*)&pc)[r];                        \
            const float pdr = ((const float*)&pd)[r];                        \
            _Pragma("unroll")                                                \
            for (int j = 0; j < 4; ++j) {                                    \
                a4[r][j] = fmaf(par, ((const float*)&C0)[j], a4[r][j]);      \
                a4[r][j] = fmaf(pbr, ((const float*)&C1)[j], a4[r][j]);      \
                a4[r][j] = fmaf(pcr, ((const float*)&C2)[j], a4[r][j]);      \
                a4[r][j] = fmaf(pdr, ((const float*)&C3)[j], a4[r][j]);      \
            }                                                                \
        }                                                                    \
    }

#pragma unroll 1
    for (int i = 0; i < 32; i += 8) {
        PH4_QUAD(WA0, WA1, WA2, WA3, ebase + i)
        if (i + 8 < 32) {
            WA0 = LDW(i + 8);  WA1 = LDW(i + 9);
            WA2 = LDW(i + 10); WA3 = LDW(i + 11);
        }
        PH4_QUAD(WB0, WB1, WB2, WB3, ebase + i + 4)
        if (i + 8 < 32) {
            WB0 = LDW(i + 12); WB1 = LDW(i + 13);
            WB2 = LDW(i + 14); WB3 = LDW(i + 15);
        }
    }
#pragma unroll
    for (int r = 0; r < 4; ++r)
        *(float4*)&p4c[eq][r][hq] = make_float4(a4[r][0], a4[r][1], a4[r][2], a4[r][3]);
    __syncthreads();

    // final combine: thread = (h, row-pair)
    const int h = tid & 511;
    const int rp = tid >> 9;          // 0..1 -> rows {rp*2, rp*2+1}
#pragma unroll
    for (int rr = 0; rr < 2; ++rr) {
        const int r = rp * 2 + rr;
        float o = 0.f;
#pragma unroll
        for (int q = 0; q < 8; ++q) o += p4c[q][r][h];
        ctx[(g0 + r) * HDIM + h] = o;
    }
}

// ---------------------------------------------------------------------------
extern "C" void kernel_launch(void* const* d_in, const int* in_sizes, int n_in,
                              void* d_out, int out_size, void* d_ws, size_t ws_size,
                              hipStream_t stream) {
    const float* dec = (const float*)d_in[0];
    const float* enc = (const float*)d_in[1];
    const unsigned char* extm = (const unsigned char*)d_in[2];
    const float* Wmlp = (const float*)d_in[3];
    const float* bmlp = (const float*)d_in[4];
    const float* Wout = (const float*)d_in[5];
    // d_in[6] = b_out: additive constant, cancels in softmax

    float* ctx = (float*)d_out;                    // [B, DEC, H]
    float* attn = ctx + (size_t)B * DEC * HDIM;    // [B, DEC, ENC]

    const size_t F = (size_t)B * DEC * HDIM;       // 524288
    float* ET = (float*)d_ws;                      // [B][H][ENC] fp32
    float* Dmat = ET + F;                          // [B*DEC][H] fp32
    unsigned short* Xh_e = (unsigned short*)(Dmat + F);
    unsigned short* Xl_e = Xh_e + F;
    unsigned short* Xh_d = Xl_e + F;
    unsigned short* Xl_d = Xh_d + F;
    unsigned short* Wh_e = Xl_d + F;               // blocked-T layout, 512*512
    unsigned short* Wl_e = Wh_e + HDIM * HDIM;
    unsigned short* Wh_d = Wl_e + HDIM * HDIM;
    unsigned short* Wl_d = Wh_d + HDIM * HDIM;

    convert_kernel<<<dim3(256, 1, 4), 256, 0, stream>>>(
        enc, dec, Wmlp, Xh_e, Xl_e, Xh_d, Xl_d, Wh_e, Wl_e, Wh_d, Wl_d);
    proj_mfma_kernel<<<dim3(16, 16, 2), 256, 0, stream>>>(
        Xh_e, Xl_e, Xh_d, Xl_d, Wh_e, Wl_e, Wh_d, Wl_d, bmlp, ET, Dmat);
    attn_ctx_kernel<<<dim3(DEC / 4, 1, B), 1024, 0, stream>>>(
        Dmat, ET, Wout, enc, extm, attn, ctx);
}